// Round 1
// baseline (529.916 us; speedup 1.0000x reference)
//
#include <hip/hip_runtime.h>
#include <hip/hip_bf16.h>

typedef __attribute__((ext_vector_type(8))) short bf16x8;
typedef __attribute__((ext_vector_type(4))) float f32x4;
typedef unsigned short u16;

#define S_LEN 4096
#define DM 1024
#define NH 16
#define DH 64

__device__ __forceinline__ u16 f2b(float f) {
  __hip_bfloat16 h = __float2bfloat16(f);
  u16 u;
  __builtin_memcpy(&u, &h, 2);
  return u;
}
__device__ __forceinline__ float b2f(u16 u) {
  __hip_bfloat16 h;
  __builtin_memcpy(&h, &u, 2);
  return __bfloat162float(h);
}

// ---------------- fp32 -> bf16 ----------------
__global__ __launch_bounds__(256) void cvt_kernel(const float* __restrict__ in,
                                                  u16* __restrict__ out, int n) {
  int i = (blockIdx.x * 256 + threadIdx.x) * 4;
  if (i >= n) return;
  float4 v = *(const float4*)(in + i);
  ushort4 o;
  o.x = f2b(v.x); o.y = f2b(v.y); o.z = f2b(v.z); o.w = f2b(v.w);
  *(ushort4*)(out + i) = o;
}

// ---------------- NT GEMM: C[M][N] = A[M][K] * B[N][K]^T (bf16 in, fp32 acc) ----
template <typename OutT>
__global__ __launch_bounds__(256) void gemm_nt(const u16* __restrict__ A,
                                               const u16* __restrict__ B,
                                               OutT* __restrict__ C,
                                               int M, int N, int K) {
  __shared__ u16 As[128 * 32];
  __shared__ u16 Bs[128 * 32];
  const int tid = threadIdx.x;
  const int wave = tid >> 6, lane = tid & 63;
  const int fm = lane & 15, fq = lane >> 4;
  const int mb = blockIdx.y * 128, nb = blockIdx.x * 128;
  const int wm = (wave & 1) * 64, wn = (wave >> 1) * 64;

  f32x4 acc[4][4];
#pragma unroll
  for (int i = 0; i < 4; ++i)
#pragma unroll
    for (int j = 0; j < 4; ++j)
#pragma unroll
      for (int r = 0; r < 4; ++r) acc[i][j][r] = 0.f;

  const int r0 = tid >> 2, c0 = (tid & 3) * 8;
  const u16* Ag0 = A + (size_t)(mb + r0) * K + c0;
  const u16* Ag1 = A + (size_t)(mb + r0 + 64) * K + c0;
  const u16* Bg0 = B + (size_t)(nb + r0) * K + c0;
  const u16* Bg1 = B + (size_t)(nb + r0 + 64) * K + c0;

  for (int k0 = 0; k0 < K; k0 += 32) {
    uint4 a0 = *(const uint4*)(Ag0 + k0);
    uint4 a1 = *(const uint4*)(Ag1 + k0);
    uint4 b0 = *(const uint4*)(Bg0 + k0);
    uint4 b1 = *(const uint4*)(Bg1 + k0);
    __syncthreads();
    *(uint4*)(As + r0 * 32 + c0) = a0;
    *(uint4*)(As + (r0 + 64) * 32 + c0) = a1;
    *(uint4*)(Bs + r0 * 32 + c0) = b0;
    *(uint4*)(Bs + (r0 + 64) * 32 + c0) = b1;
    __syncthreads();
    bf16x8 av[4], bv[4];
#pragma unroll
    for (int t = 0; t < 4; ++t) {
      av[t] = *(const bf16x8*)(As + (wm + t * 16 + fm) * 32 + fq * 8);
      bv[t] = *(const bf16x8*)(Bs + (wn + t * 16 + fm) * 32 + fq * 8);
    }
#pragma unroll
    for (int i = 0; i < 4; ++i)
#pragma unroll
      for (int j = 0; j < 4; ++j)
        acc[i][j] = __builtin_amdgcn_mfma_f32_16x16x32_bf16(av[i], bv[j], acc[i][j], 0, 0, 0);
  }
#pragma unroll
  for (int i = 0; i < 4; ++i) {
#pragma unroll
    for (int j = 0; j < 4; ++j) {
#pragma unroll
      for (int r = 0; r < 4; ++r) {
        int row = mb + wm + i * 16 + fq * 4 + r;
        int col = nb + wn + j * 16 + fm;
        if constexpr (sizeof(OutT) == 4) {
          C[(size_t)row * N + col] = (OutT)acc[i][j][r];
        } else {
          C[(size_t)row * N + col] = (OutT)f2b(acc[i][j][r]);
        }
      }
    }
  }
}

// ---------------- RoPE in-place on Q,K; folds 1/sqrt(Dh) into Q -------------
__global__ __launch_bounds__(256) void rope_kernel(u16* __restrict__ Q, u16* __restrict__ K) {
  int id = blockIdx.x * 256 + threadIdx.x;  // S*NH*32 threads
  int i = id & 31;
  int h = (id >> 5) & 15;
  int s = id >> 9;
  float inv_freq = __expf((float)i * (-9.2103403719761836f / 32.f));  // 10000^(-i/32)
  float ang = (float)s * inv_freq;
  float sn, c;
  sincosf(ang, &sn, &c);
  size_t base = (size_t)s * DM + h * DH + i;
  float q1 = b2f(Q[base]), q2 = b2f(Q[base + 32]);
  float k1 = b2f(K[base]), k2 = b2f(K[base + 32]);
  const float qs = 0.125f;  // 1/sqrt(64), folded here instead of on scores
  Q[base]      = f2b((q1 * c - q2 * sn) * qs);
  Q[base + 32] = f2b((q2 * c + q1 * sn) * qs);
  K[base]      = f2b(k1 * c - k2 * sn);
  K[base + 32] = f2b(k2 * c + k1 * sn);
}

// ---------------- V transpose: V[s][c] -> Vt[c][s] --------------------------
__global__ void transpose_v(const u16* __restrict__ V, u16* __restrict__ Vt) {
  __shared__ u16 t[32][33];
  int tx = threadIdx.x, ty = threadIdx.y;
  int c = blockIdx.x * 32, s = blockIdx.y * 32;
  t[ty][tx] = V[(size_t)(s + ty) * DM + c + tx];
  __syncthreads();
  Vt[(size_t)(c + ty) * S_LEN + s + tx] = t[tx][ty];
}

// ---------------- causal flash attention ------------------------------------
// block = 4 waves; wave w handles q rows [qb, qb+16); 32-key tiles staged in LDS.
__global__ __launch_bounds__(256) void attn_kernel(const u16* __restrict__ Q,
                                                   const u16* __restrict__ K,
                                                   const u16* __restrict__ Vt,
                                                   u16* __restrict__ Ctx) {
  __shared__ u16 Ks[32 * 72];      // [key][d], row stride 72 (pad vs 64)
  __shared__ u16 Vs[64 * 40];      // [d][key], row stride 40 (pad vs 32)
  __shared__ u16 Ps[4][16 * 40];   // per-wave P tile [qrow][key], stride 40
  const int tid = threadIdx.x;
  const int w = tid >> 6, lane = tid & 63;
  const int fm = lane & 15, fq = lane >> 4;
  const int qt = 63 - blockIdx.x;  // big blocks dispatch first -> load balance
  const int h = blockIdx.y;
  const int qb0 = qt * 64;
  const int qb = qb0 + w * 16;

  bf16x8 aq0, aq1;
  {
    const u16* qp = Q + (size_t)(qb + fm) * DM + h * DH + fq * 8;
    aq0 = *(const bf16x8*)(qp);
    aq1 = *(const bf16x8*)(qp + 32);
  }
  f32x4 o[4];
  float m_i[4], l_i[4];
#pragma unroll
  for (int r = 0; r < 4; ++r) { m_i[r] = -1e30f; l_i[r] = 0.f; }
#pragma unroll
  for (int c4 = 0; c4 < 4; ++c4)
#pragma unroll
    for (int r = 0; r < 4; ++r) o[c4][r] = 0.f;

  const int ntiles = qb0 / 32 + 2;
  const int krow = tid >> 3, kcol = (tid & 7) * 8;
  const int vrow = tid >> 2, vcol = (tid & 3) * 8;
  const u16* Kg = K + (size_t)krow * DM + h * DH + kcol;
  const u16* Vg = Vt + (size_t)(h * DH + vrow) * S_LEN + vcol;
  u16* Pw = &Ps[w][0];
  const f32x4 zf = {0.f, 0.f, 0.f, 0.f};

  for (int kt = 0; kt < ntiles; ++kt) {
    uint4 kv = *(const uint4*)(Kg + (size_t)(kt * 32) * DM);
    uint4 vv = *(const uint4*)(Vg + kt * 32);
    __syncthreads();
    *(uint4*)(Ks + krow * 72 + kcol) = kv;
    *(uint4*)(Vs + vrow * 40 + vcol) = vv;
    __syncthreads();

    // S = Q * K^T  (two 16-key fragments)
    bf16x8 bk00 = *(const bf16x8*)(Ks + fm * 72 + fq * 8);
    bf16x8 bk01 = *(const bf16x8*)(Ks + fm * 72 + 32 + fq * 8);
    bf16x8 bk10 = *(const bf16x8*)(Ks + (16 + fm) * 72 + fq * 8);
    bf16x8 bk11 = *(const bf16x8*)(Ks + (16 + fm) * 72 + 32 + fq * 8);
    f32x4 s0 = __builtin_amdgcn_mfma_f32_16x16x32_bf16(aq0, bk00, zf, 0, 0, 0);
    s0 = __builtin_amdgcn_mfma_f32_16x16x32_bf16(aq1, bk01, s0, 0, 0, 0);
    f32x4 s1 = __builtin_amdgcn_mfma_f32_16x16x32_bf16(aq0, bk10, zf, 0, 0, 0);
    s1 = __builtin_amdgcn_mfma_f32_16x16x32_bf16(aq1, bk11, s1, 0, 0, 0);

    // online softmax (per C-layout row = fq*4 + r, cols across the 16-lane group)
    float al[4];
#pragma unroll
    for (int r = 0; r < 4; ++r) {
      int qg = qb + fq * 4 + r;
      int kg0 = kt * 32 + fm;
      float v0 = (kg0 > qg) ? -1e30f : s0[r];
      float v1 = (kg0 + 16 > qg) ? -1e30f : s1[r];
      float mx = fmaxf(v0, v1);
      mx = fmaxf(mx, __shfl_xor(mx, 1));
      mx = fmaxf(mx, __shfl_xor(mx, 2));
      mx = fmaxf(mx, __shfl_xor(mx, 4));
      mx = fmaxf(mx, __shfl_xor(mx, 8));
      float mn = fmaxf(m_i[r], mx);
      float a = __expf(m_i[r] - mn);
      m_i[r] = mn;
      float p0 = __expf(v0 - mn);
      float p1 = __expf(v1 - mn);
      float rs = p0 + p1;
      rs += __shfl_xor(rs, 1);
      rs += __shfl_xor(rs, 2);
      rs += __shfl_xor(rs, 4);
      rs += __shfl_xor(rs, 8);
      l_i[r] = l_i[r] * a + rs;
      al[r] = a;
      // P: C-layout -> LDS (A-layout readback below)
      Pw[(fq * 4 + r) * 40 + fm] = f2b(p0);
      Pw[(fq * 4 + r) * 40 + 16 + fm] = f2b(p1);
    }
#pragma unroll
    for (int c4 = 0; c4 < 4; ++c4)
#pragma unroll
      for (int r = 0; r < 4; ++r) o[c4][r] *= al[r];

    asm volatile("s_waitcnt lgkmcnt(0)" ::: "memory");
    bf16x8 ap = *(const bf16x8*)(Pw + fm * 40 + fq * 8);
#pragma unroll
    for (int c4 = 0; c4 < 4; ++c4) {
      bf16x8 bv = *(const bf16x8*)(Vs + (c4 * 16 + fm) * 40 + fq * 8);
      o[c4] = __builtin_amdgcn_mfma_f32_16x16x32_bf16(ap, bv, o[c4], 0, 0, 0);
    }
  }
#pragma unroll
  for (int c4 = 0; c4 < 4; ++c4) {
#pragma unroll
    for (int r = 0; r < 4; ++r) {
      int row = qb + fq * 4 + r;
      int col = h * DH + c4 * 16 + fm;
      Ctx[(size_t)row * DM + col] = f2b(o[c4][r] / l_i[r]);
    }
  }
}

extern "C" void kernel_launch(void* const* d_in, const int* in_sizes, int n_in,
                              void* d_out, int out_size, void* d_ws, size_t ws_size,
                              hipStream_t stream) {
  const float* x  = (const float*)d_in[0];
  const float* Wq = (const float*)d_in[1];
  const float* Wk = (const float*)d_in[2];
  const float* Wv = (const float*)d_in[3];
  const float* Wo = (const float*)d_in[4];
  float* out = (float*)d_out;

  const size_t MB = 1u << 20;
  char* ws = (char*)d_ws;
  u16* xb  = (u16*)(ws + 0 * MB);   // 8 MB
  u16* wqb = (u16*)(ws + 8 * MB);   // 2 MB
  u16* wkb = (u16*)(ws + 10 * MB);
  u16* wvb = (u16*)(ws + 12 * MB);
  u16* wob = (u16*)(ws + 14 * MB);
  u16* Qb  = (u16*)(ws + 16 * MB);  // 8 MB each
  u16* Kb  = (u16*)(ws + 24 * MB);
  u16* Vb  = (u16*)(ws + 32 * MB);
  u16* Vtb = (u16*)(ws + 40 * MB);
  u16* Ctx = (u16*)(ws + 48 * MB);

  const int n_x = S_LEN * DM;      // 4194304
  const int n_w = DM * DM;         // 1048576

  cvt_kernel<<<n_x / 1024, 256, 0, stream>>>(x, xb, n_x);
  cvt_kernel<<<n_w / 1024, 256, 0, stream>>>(Wq, wqb, n_w);
  cvt_kernel<<<n_w / 1024, 256, 0, stream>>>(Wk, wkb, n_w);
  cvt_kernel<<<n_w / 1024, 256, 0, stream>>>(Wv, wvb, n_w);
  cvt_kernel<<<n_w / 1024, 256, 0, stream>>>(Wo, wob, n_w);

  dim3 gg(DM / 128, S_LEN / 128);  // (8, 32)
  gemm_nt<u16><<<gg, 256, 0, stream>>>(xb, wqb, Qb, S_LEN, DM, DM);
  gemm_nt<u16><<<gg, 256, 0, stream>>>(xb, wkb, Kb, S_LEN, DM, DM);
  gemm_nt<u16><<<gg, 256, 0, stream>>>(xb, wvb, Vb, S_LEN, DM, DM);

  rope_kernel<<<(S_LEN * NH * 32) / 256, 256, 0, stream>>>(Qb, Kb);
  transpose_v<<<dim3(DM / 32, S_LEN / 32), dim3(32, 32), 0, stream>>>(Vb, Vtb);
  attn_kernel<<<dim3(S_LEN / 64, NH), 256, 0, stream>>>(Qb, Kb, Vtb, Ctx);

  gemm_nt<float><<<gg, 256, 0, stream>>>(Ctx, wob, out, S_LEN, DM, DM);
}

// Round 2
// 405.371 us; speedup vs baseline: 1.3072x; 1.3072x over previous
//
#include <hip/hip_runtime.h>
#include <hip/hip_bf16.h>

typedef __attribute__((ext_vector_type(8))) short bf16x8;
typedef __attribute__((ext_vector_type(4))) float f32x4;
typedef unsigned short u16;

#define S_LEN 4096
#define DM 1024
#define NH 16
#define DH 64

__device__ __forceinline__ u16 f2b(float f) {
  __hip_bfloat16 h = __float2bfloat16(f);
  u16 u;
  __builtin_memcpy(&u, &h, 2);
  return u;
}
__device__ __forceinline__ float b2f(u16 u) {
  __hip_bfloat16 h;
  __builtin_memcpy(&h, &u, 2);
  return __bfloat162float(h);
}

// global -> LDS direct (16B per lane; lds base must be wave-uniform)
__device__ __forceinline__ void glds16(const u16* g, u16* l) {
  __builtin_amdgcn_global_load_lds(
      (const __attribute__((address_space(1))) unsigned int*)g,
      (__attribute__((address_space(3))) unsigned int*)l, 16, 0, 0);
}

// ---------------- fp32 -> bf16 ----------------
__global__ __launch_bounds__(256) void cvt_kernel(const float* __restrict__ in,
                                                  u16* __restrict__ out, int n) {
  int i = (blockIdx.x * 256 + threadIdx.x) * 4;
  if (i >= n) return;
  float4 v = *(const float4*)(in + i);
  ushort4 o;
  o.x = f2b(v.x); o.y = f2b(v.y); o.z = f2b(v.z); o.w = f2b(v.w);
  *(ushort4*)(out + i) = o;
}

__global__ __launch_bounds__(256) void cvt4_kernel(const float* __restrict__ a,
                                                   const float* __restrict__ b,
                                                   const float* __restrict__ c,
                                                   const float* __restrict__ d,
                                                   u16* __restrict__ oa, u16* __restrict__ ob,
                                                   u16* __restrict__ oc, u16* __restrict__ od) {
  const float* ins[4] = {a, b, c, d};
  u16* outs[4] = {oa, ob, oc, od};
  int w = blockIdx.y;
  int i = (blockIdx.x * 256 + threadIdx.x) * 4;
  float4 v = *(const float4*)(ins[w] + i);
  ushort4 o;
  o.x = f2b(v.x); o.y = f2b(v.y); o.z = f2b(v.z); o.w = f2b(v.w);
  *(ushort4*)(outs[w] + i) = o;
}

// ---------------- NT GEMM: C[M][N] = A[M][K] * B[N][K]^T ----------------
// m97 structure: global_load_lds staging, XOR-swizzled LDS, double-buffered,
// one barrier per K-step.
template <typename OutT>
__global__ __launch_bounds__(256) void gemm_nt(const u16* __restrict__ A,
                                               const u16* __restrict__ B,
                                               OutT* __restrict__ C,
                                               int M, int N, int K) {
  __shared__ __align__(16) u16 As[2 * 128 * 32];
  __shared__ __align__(16) u16 Bs[2 * 128 * 32];
  const int tid = threadIdx.x;
  const int wave = tid >> 6, lane = tid & 63;
  const int fm = lane & 15, fq = lane >> 4;
  const int mb = blockIdx.y * 128, nb = blockIdx.x * 128;
  const int wm = (wave & 1) * 64, wn = (wave >> 1) * 64;

  f32x4 acc[4][4];
#pragma unroll
  for (int i = 0; i < 4; ++i)
#pragma unroll
    for (int j = 0; j < 4; ++j)
#pragma unroll
      for (int r = 0; r < 4; ++r) acc[i][j][r] = 0.f;

  // staging map: slot s = call*256 + tid; row r = s>>2; stored chunk = s&3;
  // global chunk cg = (s&3) ^ ((r>>1)&3)  (same for both calls since r1 = r0+64)
  const int r_ = tid >> 2;
  const int cg = (tid & 3) ^ ((r_ >> 1) & 3);
  const u16* Ag0 = A + (size_t)(mb + r_) * K + cg * 8;
  const u16* Ag1 = A + (size_t)(mb + r_ + 64) * K + cg * 8;
  const u16* Bg0 = B + (size_t)(nb + r_) * K + cg * 8;
  const u16* Bg1 = B + (size_t)(nb + r_ + 64) * K + cg * 8;
  const int l0 = wave * 512;         // u16 offset, wave-uniform
  const int l1 = 2048 + wave * 512;

  const int sw = (fm >> 1) & 3;      // read-side swizzle selector

  int buf = 0;
  // preload k0 = 0
  glds16(Ag0, As + l0);
  glds16(Ag1, As + l1);
  glds16(Bg0, Bs + l0);
  glds16(Bg1, Bs + l1);

  for (int k0 = 0; k0 < K; k0 += 32) {
    __syncthreads();  // drains vmcnt -> LDS[buf] ready; also protects buf^1
    if (k0 + 32 < K) {
      int bo = (buf ^ 1) * 4096;
      glds16(Ag0 + k0 + 32, As + bo + l0);
      glds16(Ag1 + k0 + 32, As + bo + l1);
      glds16(Bg0 + k0 + 32, Bs + bo + l0);
      glds16(Bg1 + k0 + 32, Bs + bo + l1);
    }
    const u16* Ab = As + buf * 4096;
    const u16* Bb = Bs + buf * 4096;
    bf16x8 av[4], bv[4];
#pragma unroll
    for (int t = 0; t < 4; ++t) {
      av[t] = *(const bf16x8*)(Ab + (wm + t * 16 + fm) * 32 + ((fq ^ sw) * 8));
      bv[t] = *(const bf16x8*)(Bb + (wn + t * 16 + fm) * 32 + ((fq ^ sw) * 8));
    }
#pragma unroll
    for (int i = 0; i < 4; ++i)
#pragma unroll
      for (int j = 0; j < 4; ++j)
        acc[i][j] = __builtin_amdgcn_mfma_f32_16x16x32_bf16(av[i], bv[j], acc[i][j], 0, 0, 0);
    buf ^= 1;
  }
#pragma unroll
  for (int i = 0; i < 4; ++i) {
#pragma unroll
    for (int j = 0; j < 4; ++j) {
#pragma unroll
      for (int r = 0; r < 4; ++r) {
        int row = mb + wm + i * 16 + fq * 4 + r;
        int col = nb + wn + j * 16 + fm;
        if constexpr (sizeof(OutT) == 4) {
          C[(size_t)row * N + col] = (OutT)acc[i][j][r];
        } else {
          C[(size_t)row * N + col] = (OutT)f2b(acc[i][j][r]);
        }
      }
    }
  }
}

// ---------------- RoPE in-place; folds (1/sqrt(Dh))*log2(e) into Q ---------
__global__ __launch_bounds__(256) void rope_kernel(u16* __restrict__ Q, u16* __restrict__ K) {
  int id = blockIdx.x * 256 + threadIdx.x;  // S*NH*32 threads
  int i = id & 31;
  int h = (id >> 5) & 15;
  int s = id >> 9;
  float inv_freq = __expf((float)i * (-9.2103403719761836f / 32.f));  // 10000^(-i/32)
  float ang = (float)s * inv_freq;
  float sn, c;
  sincosf(ang, &sn, &c);
  size_t base = (size_t)s * DM + h * DH + i;
  float q1 = b2f(Q[base]), q2 = b2f(Q[base + 32]);
  float k1 = b2f(K[base]), k2 = b2f(K[base + 32]);
  const float qs = 0.125f * 1.4426950408889634f;  // 1/sqrt(64) * log2(e): exp2 softmax
  Q[base]      = f2b((q1 * c - q2 * sn) * qs);
  Q[base + 32] = f2b((q2 * c + q1 * sn) * qs);
  K[base]      = f2b(k1 * c - k2 * sn);
  K[base + 32] = f2b(k2 * c + k1 * sn);
}

// ---------------- V transpose: V[s][c] -> Vt[c][s] --------------------------
__global__ void transpose_v(const u16* __restrict__ V, u16* __restrict__ Vt) {
  __shared__ u16 t[32][33];
  int tx = threadIdx.x, ty = threadIdx.y;
  int c = blockIdx.x * 32, s = blockIdx.y * 32;
  t[ty][tx] = V[(size_t)(s + ty) * DM + c + tx];
  __syncthreads();
  Vt[(size_t)(c + ty) * S_LEN + s + tx] = t[tx][ty];
}

// ---------------- causal flash attention ------------------------------------
// 4 waves x 16 q-rows; 64-key tiles, double-buffered global_load_lds staging
// with XOR swizzle (chunk ^= row&7), ONE barrier per tile. exp2-domain softmax.
__global__ __launch_bounds__(256) void attn_kernel(const u16* __restrict__ Q,
                                                   const u16* __restrict__ K,
                                                   const u16* __restrict__ Vt,
                                                   u16* __restrict__ Ctx) {
  __shared__ __align__(16) u16 Ks[2 * 64 * 64];   // [key][d], 8 chunks/row, swizzled
  __shared__ __align__(16) u16 Vs[2 * 64 * 64];   // [d][key], swizzled
  __shared__ __align__(16) u16 Ps[4][16 * 72];    // per-wave P [qrow][key], stride 72
  const int tid = threadIdx.x;
  const int w = tid >> 6, lane = tid & 63;
  const int fm = lane & 15, fq = lane >> 4;
  const int qt = 63 - blockIdx.x;  // big blocks dispatch first
  const int h = blockIdx.y;
  const int qb = qt * 64 + w * 16;
  const int ntiles = qt + 1;       // 64-key tiles

  bf16x8 aq0, aq1;
  {
    const u16* qp = Q + (size_t)(qb + fm) * DM + h * DH + fq * 8;
    aq0 = *(const bf16x8*)(qp);
    aq1 = *(const bf16x8*)(qp + 32);
  }
  f32x4 o[4];
  float m_i[4], l_i[4];
#pragma unroll
  for (int r = 0; r < 4; ++r) { m_i[r] = -1e30f; l_i[r] = 0.f; }
#pragma unroll
  for (int c4 = 0; c4 < 4; ++c4)
#pragma unroll
    for (int r = 0; r < 4; ++r) o[c4][r] = 0.f;

  // staging: 512 slots of 16B per tile; slot s = call*256 + tid.
  // r = s>>3 (row), stored chunk = s&7, global chunk = (s&7) ^ (r&7).
  const int rr = tid >> 3;                    // 0..31
  const int cc8 = (tid & 7) ^ (rr & 7);       // same for both calls (r1 = rr+32)
  const u16* Kg0 = K + (size_t)rr * DM + h * DH + cc8 * 8;
  const u16* Kg1 = K + (size_t)(rr + 32) * DM + h * DH + cc8 * 8;
  const u16* Vg0 = Vt + (size_t)(h * DH + rr) * S_LEN + cc8 * 8;
  const u16* Vg1 = Vt + (size_t)(h * DH + rr + 32) * S_LEN + cc8 * 8;
  const int l0 = w * 512;                     // u16, wave-uniform
  const int l1 = 2048 + w * 512;
  const int sw7 = fm & 7;                     // read-side swizzle selector
  u16* Pw = &Ps[w][0];
  const f32x4 zf = {0.f, 0.f, 0.f, 0.f};

  // preload tile 0
  glds16(Kg0, Ks + l0);
  glds16(Kg1, Ks + l1);
  glds16(Vg0, Vs + l0);
  glds16(Vg1, Vs + l1);

  int buf = 0;
  for (int kt = 0; kt < ntiles; ++kt) {
    __syncthreads();  // drains prefetch; LDS[buf] ready
    if (kt + 1 < ntiles) {
      int bo = (buf ^ 1) * 4096;
      size_t ko = (size_t)(kt + 1) * 64 * DM;
      int vo = (kt + 1) * 64;
      glds16(Kg0 + ko, Ks + bo + l0);
      glds16(Kg1 + ko, Ks + bo + l1);
      glds16(Vg0 + vo, Vs + bo + l0);
      glds16(Vg1 + vo, Vs + bo + l1);
    }
    const u16* Kb = Ks + buf * 4096;
    const u16* Vb = Vs + buf * 4096;

    // S = Q * K^T : 4 tiles of 16 keys
    f32x4 st[4];
#pragma unroll
    for (int t = 0; t < 4; ++t) {
      const u16* kr = Kb + (t * 16 + fm) * 64;
      bf16x8 b0 = *(const bf16x8*)(kr + ((fq ^ sw7) * 8));
      bf16x8 b1 = *(const bf16x8*)(kr + (((fq + 4) ^ sw7) * 8));
      st[t] = __builtin_amdgcn_mfma_f32_16x16x32_bf16(aq0, b0, zf, 0, 0, 0);
      st[t] = __builtin_amdgcn_mfma_f32_16x16x32_bf16(aq1, b1, st[t], 0, 0, 0);
    }
    // causal mask: only the last tile of each block straddles the diagonal
    if (kt == ntiles - 1) {
#pragma unroll
      for (int t = 0; t < 4; ++t) {
        int key = kt * 64 + t * 16 + fm;
#pragma unroll
        for (int r = 0; r < 4; ++r) {
          int qg = qb + fq * 4 + r;
          st[t][r] = (key > qg) ? -1e30f : st[t][r];
        }
      }
    }
    // online softmax (exp2 domain; log2e folded into Q scale)
    float al[4];
#pragma unroll
    for (int r = 0; r < 4; ++r) {
      float v0 = st[0][r], v1 = st[1][r], v2 = st[2][r], v3 = st[3][r];
      float mx = fmaxf(fmaxf(v0, v1), fmaxf(v2, v3));
      mx = fmaxf(mx, __shfl_xor(mx, 1));
      mx = fmaxf(mx, __shfl_xor(mx, 2));
      mx = fmaxf(mx, __shfl_xor(mx, 4));
      mx = fmaxf(mx, __shfl_xor(mx, 8));
      float mn = fmaxf(m_i[r], mx);
      float a = exp2f(m_i[r] - mn);
      m_i[r] = mn;
      float p0 = exp2f(v0 - mn), p1 = exp2f(v1 - mn);
      float p2 = exp2f(v2 - mn), p3 = exp2f(v3 - mn);
      float rs = (p0 + p1) + (p2 + p3);
      rs += __shfl_xor(rs, 1);
      rs += __shfl_xor(rs, 2);
      rs += __shfl_xor(rs, 4);
      rs += __shfl_xor(rs, 8);
      l_i[r] = l_i[r] * a + rs;
      al[r] = a;
      int prow = (fq * 4 + r) * 72;
      Pw[prow + fm] = f2b(p0);
      Pw[prow + 16 + fm] = f2b(p1);
      Pw[prow + 32 + fm] = f2b(p2);
      Pw[prow + 48 + fm] = f2b(p3);
    }
#pragma unroll
    for (int c4 = 0; c4 < 4; ++c4)
#pragma unroll
      for (int r = 0; r < 4; ++r) o[c4][r] *= al[r];

    asm volatile("s_waitcnt lgkmcnt(0)" ::: "memory");
    bf16x8 ap0 = *(const bf16x8*)(Pw + fm * 72 + fq * 8);
    bf16x8 ap1 = *(const bf16x8*)(Pw + fm * 72 + 32 + fq * 8);
#pragma unroll
    for (int c4 = 0; c4 < 4; ++c4) {
      const u16* vr = Vb + (c4 * 16 + fm) * 64;
      bf16x8 bv0 = *(const bf16x8*)(vr + ((fq ^ sw7) * 8));
      bf16x8 bv1 = *(const bf16x8*)(vr + (((fq + 4) ^ sw7) * 8));
      o[c4] = __builtin_amdgcn_mfma_f32_16x16x32_bf16(ap0, bv0, o[c4], 0, 0, 0);
      o[c4] = __builtin_amdgcn_mfma_f32_16x16x32_bf16(ap1, bv1, o[c4], 0, 0, 0);
    }
    buf ^= 1;
  }
#pragma unroll
  for (int c4 = 0; c4 < 4; ++c4) {
#pragma unroll
    for (int r = 0; r < 4; ++r) {
      int row = qb + fq * 4 + r;
      int col = h * DH + c4 * 16 + fm;
      Ctx[(size_t)row * DM + col] = f2b(o[c4][r] / l_i[r]);
    }
  }
}

extern "C" void kernel_launch(void* const* d_in, const int* in_sizes, int n_in,
                              void* d_out, int out_size, void* d_ws, size_t ws_size,
                              hipStream_t stream) {
  const float* x  = (const float*)d_in[0];
  const float* Wq = (const float*)d_in[1];
  const float* Wk = (const float*)d_in[2];
  const float* Wv = (const float*)d_in[3];
  const float* Wo = (const float*)d_in[4];
  float* out = (float*)d_out;

  const size_t MB = 1u << 20;
  char* ws = (char*)d_ws;
  u16* xb  = (u16*)(ws + 0 * MB);   // 8 MB
  u16* wqb = (u16*)(ws + 8 * MB);   // 2 MB
  u16* wkb = (u16*)(ws + 10 * MB);
  u16* wvb = (u16*)(ws + 12 * MB);
  u16* wob = (u16*)(ws + 14 * MB);
  u16* Qb  = (u16*)(ws + 16 * MB);  // 8 MB each
  u16* Kb  = (u16*)(ws + 24 * MB);
  u16* Vb  = (u16*)(ws + 32 * MB);
  u16* Vtb = (u16*)(ws + 40 * MB);
  u16* Ctx = (u16*)(ws + 48 * MB);

  const int n_x = S_LEN * DM;      // 4194304
  const int n_w = DM * DM;         // 1048576

  cvt_kernel<<<n_x / 1024, 256, 0, stream>>>(x, xb, n_x);
  cvt4_kernel<<<dim3(n_w / 1024, 4), 256, 0, stream>>>(Wq, Wk, Wv, Wo, wqb, wkb, wvb, wob);

  dim3 gg(DM / 128, S_LEN / 128);  // (8, 32)
  gemm_nt<u16><<<gg, 256, 0, stream>>>(xb, wqb, Qb, S_LEN, DM, DM);
  gemm_nt<u16><<<gg, 256, 0, stream>>>(xb, wkb, Kb, S_LEN, DM, DM);
  gemm_nt<u16><<<gg, 256, 0, stream>>>(xb, wvb, Vb, S_LEN, DM, DM);

  rope_kernel<<<(S_LEN * NH * 32) / 256, 256, 0, stream>>>(Qb, Kb);
  transpose_v<<<dim3(DM / 32, S_LEN / 32), dim3(32, 32), 0, stream>>>(Vb, Vtb);
  attn_kernel<<<dim3(S_LEN / 64, NH), 256, 0, stream>>>(Qb, Kb, Vtb, Ctx);

  gemm_nt<float><<<gg, 256, 0, stream>>>(Ctx, wob, out, S_LEN, DM, DM);
}

// Round 3
// 279.382 us; speedup vs baseline: 1.8967x; 1.4510x over previous
//
#include <hip/hip_runtime.h>
#include <hip/hip_bf16.h>

typedef __attribute__((ext_vector_type(8))) short bf16x8;
typedef __attribute__((ext_vector_type(4))) float f32x4;
typedef unsigned short u16;

#define S_LEN 4096
#define DM 1024
#define NH 16
#define DH 64
#define PSTR 72

__device__ __forceinline__ u16 f2b(float f) {
  __hip_bfloat16 h = __float2bfloat16(f);
  u16 u;
  __builtin_memcpy(&u, &h, 2);
  return u;
}

// global -> LDS direct (16B per lane; lds base must be wave-uniform)
__device__ __forceinline__ void glds16(const u16* g, u16* l) {
  __builtin_amdgcn_global_load_lds(
      (const __attribute__((address_space(1))) unsigned int*)g,
      (__attribute__((address_space(3))) unsigned int*)l, 16, 0, 0);
}

// ---------------- fp32 -> bf16, all 5 inputs in one launch ----------------
__global__ __launch_bounds__(256) void cvt_all(const float* __restrict__ x,
                                               const float* __restrict__ Wq,
                                               const float* __restrict__ Wk,
                                               const float* __restrict__ Wv,
                                               const float* __restrict__ Wo,
                                               u16* __restrict__ xb, u16* __restrict__ wqb,
                                               u16* __restrict__ wkb, u16* __restrict__ wvb,
                                               u16* __restrict__ wob) {
  int idx = (blockIdx.x * 256 + threadIdx.x) * 4;
  const float* src;
  u16* dst;
  int o;
  if (idx < 4194304) {
    src = x; dst = xb; o = idx;
  } else {
    int t = idx - 4194304;
    int wsel = t >> 20;
    o = t & 1048575;
    src = (wsel == 0) ? Wq : (wsel == 1) ? Wk : (wsel == 2) ? Wv : Wo;
    dst = (wsel == 0) ? wqb : (wsel == 1) ? wkb : (wsel == 2) ? wvb : wob;
  }
  float4 v = *(const float4*)(src + o);
  ushort4 ov;
  ov.x = f2b(v.x); ov.y = f2b(v.y); ov.z = f2b(v.z); ov.w = f2b(v.w);
  *(ushort4*)(dst + o) = ov;
}

// ---------------- fused QKV NT-GEMM with RoPE epilogue ----------------
// grid (24, 32): mat = bx>>3 (0=Q rope+scale, 1=K rope, 2=V plain), nb = (bx&7)*128
__global__ __launch_bounds__(256) void qkv_gemm(const u16* __restrict__ A,
                                                const u16* __restrict__ Wq,
                                                const u16* __restrict__ Wk,
                                                const u16* __restrict__ Wv,
                                                u16* __restrict__ Qo, u16* __restrict__ Ko,
                                                u16* __restrict__ Vo) {
  __shared__ __align__(16) u16 As[2 * 128 * 32];
  __shared__ __align__(16) u16 Bs[2 * 128 * 32];
  const int mat = blockIdx.x >> 3;
  const u16* B = (mat == 0) ? Wq : (mat == 1) ? Wk : Wv;
  u16* Out = (mat == 0) ? Qo : (mat == 1) ? Ko : Vo;
  const int K = DM, N = DM;
  const int tid = threadIdx.x;
  const int wave = tid >> 6, lane = tid & 63;
  const int fm = lane & 15, fq = lane >> 4;
  const int mb = blockIdx.y * 128, nb = (blockIdx.x & 7) * 128;
  const int wm = (wave & 1) * 64, wn = (wave >> 1) * 64;

  f32x4 acc[4][4];
#pragma unroll
  for (int i = 0; i < 4; ++i)
#pragma unroll
    for (int j = 0; j < 4; ++j)
#pragma unroll
      for (int r = 0; r < 4; ++r) acc[i][j][r] = 0.f;

  const int r_ = tid >> 2;
  const int cg = (tid & 3) ^ ((r_ >> 1) & 3);
  const u16* Ag0 = A + (size_t)(mb + r_) * K + cg * 8;
  const u16* Ag1 = A + (size_t)(mb + r_ + 64) * K + cg * 8;
  const u16* Bg0 = B + (size_t)(nb + r_) * K + cg * 8;
  const u16* Bg1 = B + (size_t)(nb + r_ + 64) * K + cg * 8;
  const int l0 = wave * 512;
  const int l1 = 2048 + wave * 512;
  const int sw = (fm >> 1) & 3;

  int buf = 0;
  glds16(Ag0, As + l0);
  glds16(Ag1, As + l1);
  glds16(Bg0, Bs + l0);
  glds16(Bg1, Bs + l1);

  for (int k0 = 0; k0 < K; k0 += 32) {
    __syncthreads();
    if (k0 + 32 < K) {
      int bo = (buf ^ 1) * 4096;
      glds16(Ag0 + k0 + 32, As + bo + l0);
      glds16(Ag1 + k0 + 32, As + bo + l1);
      glds16(Bg0 + k0 + 32, Bs + bo + l0);
      glds16(Bg1 + k0 + 32, Bs + bo + l1);
    }
    const u16* Ab = As + buf * 4096;
    const u16* Bb = Bs + buf * 4096;
    bf16x8 av[4], bv[4];
#pragma unroll
    for (int t = 0; t < 4; ++t) {
      av[t] = *(const bf16x8*)(Ab + (wm + t * 16 + fm) * 32 + ((fq ^ sw) * 8));
      bv[t] = *(const bf16x8*)(Bb + (wn + t * 16 + fm) * 32 + ((fq ^ sw) * 8));
    }
#pragma unroll
    for (int i = 0; i < 4; ++i)
#pragma unroll
      for (int j = 0; j < 4; ++j)
        acc[i][j] = __builtin_amdgcn_mfma_f32_16x16x32_bf16(av[i], bv[j], acc[i][j], 0, 0, 0);
    buf ^= 1;
  }

  // RoPE epilogue (in-register): cols pair (j, j+2) = (d, d+32), d = j*16+fm for j in {0,1}
  if (mat < 2) {
    const float qs = (mat == 0) ? 0.1803368801111204f : 1.0f;  // 0.125*log2(e) for Q
    const float c1 = -9.2103403719761836f / 32.f;              // -ln(10000)/32
    const float if0 = __expf((float)fm * c1);
    const float if1 = __expf((float)(16 + fm) * c1);
#pragma unroll
    for (int ii = 0; ii < 4; ++ii) {
#pragma unroll
      for (int r = 0; r < 4; ++r) {
        float s = (float)(mb + wm + ii * 16 + fq * 4 + r);
#pragma unroll
        for (int jp = 0; jp < 2; ++jp) {
          float ang = s * (jp ? if1 : if0);
          float sn, cs;
          __sincosf(ang, &sn, &cs);
          float a = acc[ii][jp][r], b = acc[ii][jp + 2][r];
          acc[ii][jp][r] = (a * cs - b * sn) * qs;
          acc[ii][jp + 2][r] = (b * cs + a * sn) * qs;
        }
      }
    }
  }
#pragma unroll
  for (int i = 0; i < 4; ++i)
#pragma unroll
    for (int j = 0; j < 4; ++j)
#pragma unroll
      for (int r = 0; r < 4; ++r) {
        int row = mb + wm + i * 16 + fq * 4 + r;
        int col = nb + wn + j * 16 + fm;
        Out[(size_t)row * N + col] = f2b(acc[i][j][r]);
      }
}

// ---------------- O-projection NT GEMM (fp32 out) ----------------
__global__ __launch_bounds__(256) void o_gemm(const u16* __restrict__ A,
                                              const u16* __restrict__ B,
                                              float* __restrict__ C, int M, int N, int K) {
  __shared__ __align__(16) u16 As[2 * 128 * 32];
  __shared__ __align__(16) u16 Bs[2 * 128 * 32];
  const int tid = threadIdx.x;
  const int wave = tid >> 6, lane = tid & 63;
  const int fm = lane & 15, fq = lane >> 4;
  const int mb = blockIdx.y * 128, nb = blockIdx.x * 128;
  const int wm = (wave & 1) * 64, wn = (wave >> 1) * 64;

  f32x4 acc[4][4];
#pragma unroll
  for (int i = 0; i < 4; ++i)
#pragma unroll
    for (int j = 0; j < 4; ++j)
#pragma unroll
      for (int r = 0; r < 4; ++r) acc[i][j][r] = 0.f;

  const int r_ = tid >> 2;
  const int cg = (tid & 3) ^ ((r_ >> 1) & 3);
  const u16* Ag0 = A + (size_t)(mb + r_) * K + cg * 8;
  const u16* Ag1 = A + (size_t)(mb + r_ + 64) * K + cg * 8;
  const u16* Bg0 = B + (size_t)(nb + r_) * K + cg * 8;
  const u16* Bg1 = B + (size_t)(nb + r_ + 64) * K + cg * 8;
  const int l0 = wave * 512;
  const int l1 = 2048 + wave * 512;
  const int sw = (fm >> 1) & 3;

  int buf = 0;
  glds16(Ag0, As + l0);
  glds16(Ag1, As + l1);
  glds16(Bg0, Bs + l0);
  glds16(Bg1, Bs + l1);

  for (int k0 = 0; k0 < K; k0 += 32) {
    __syncthreads();
    if (k0 + 32 < K) {
      int bo = (buf ^ 1) * 4096;
      glds16(Ag0 + k0 + 32, As + bo + l0);
      glds16(Ag1 + k0 + 32, As + bo + l1);
      glds16(Bg0 + k0 + 32, Bs + bo + l0);
      glds16(Bg1 + k0 + 32, Bs + bo + l1);
    }
    const u16* Ab = As + buf * 4096;
    const u16* Bb = Bs + buf * 4096;
    bf16x8 av[4], bv[4];
#pragma unroll
    for (int t = 0; t < 4; ++t) {
      av[t] = *(const bf16x8*)(Ab + (wm + t * 16 + fm) * 32 + ((fq ^ sw) * 8));
      bv[t] = *(const bf16x8*)(Bb + (wn + t * 16 + fm) * 32 + ((fq ^ sw) * 8));
    }
#pragma unroll
    for (int i = 0; i < 4; ++i)
#pragma unroll
      for (int j = 0; j < 4; ++j)
        acc[i][j] = __builtin_amdgcn_mfma_f32_16x16x32_bf16(av[i], bv[j], acc[i][j], 0, 0, 0);
    buf ^= 1;
  }
#pragma unroll
  for (int i = 0; i < 4; ++i)
#pragma unroll
    for (int j = 0; j < 4; ++j)
#pragma unroll
      for (int r = 0; r < 4; ++r) {
        int row = mb + wm + i * 16 + fq * 4 + r;
        int col = nb + wn + j * 16 + fm;
        C[(size_t)row * N + col] = acc[i][j][r];
      }
}

// ---------------- V transpose: V[s][c] -> Vt[c][s] --------------------------
__global__ void transpose_v(const u16* __restrict__ V, u16* __restrict__ Vt) {
  __shared__ u16 t[32][33];
  int tx = threadIdx.x, ty = threadIdx.y;
  int c = blockIdx.x * 32, s = blockIdx.y * 32;
  t[ty][tx] = V[(size_t)(s + ty) * DM + c + tx];
  __syncthreads();
  Vt[(size_t)(c + ty) * S_LEN + s + tx] = t[tx][ty];
}

// ---------------- causal flash attention v3 ---------------------------------
// 4 waves x 32 q-rows (128-q blocks); S^T orientation (QK = mfma(Kfrag,Qfrag));
// fixed-m (m=0) exp2 softmax: no max reduction, no rescale; per-lane lsum,
// single cross-lane reduce at end. 64-key tiles, dbuf global_load_lds, one
// barrier per tile. P exchange via per-wave LDS: 8x ds_write_b64, 4x read_b128.
__global__ __launch_bounds__(256) void attn_kernel(const u16* __restrict__ Q,
                                                   const u16* __restrict__ K,
                                                   const u16* __restrict__ Vt,
                                                   u16* __restrict__ Ctx) {
  __shared__ __align__(16) u16 Ks[2 * 64 * 64];
  __shared__ __align__(16) u16 Vs[2 * 64 * 64];
  __shared__ __align__(16) u16 Ps[4][2][16 * PSTR];
  const int tid = threadIdx.x;
  const int w = tid >> 6, lane = tid & 63;
  const int fm = lane & 15, fq = lane >> 4;
  const int qt = 31 - blockIdx.x;  // big blocks dispatch first
  const int h = blockIdx.y;
  const int qb = qt * 128 + w * 32;
  const int ntiles = 2 * qt + 2;
  const int dtile = qb >> 6;  // first tile that needs masking for this wave

  // Q B-operand fragments: lane n=fm -> q-row qb+g*16+fm, k=d
  bf16x8 q0[2], q1[2];
#pragma unroll
  for (int g = 0; g < 2; ++g) {
    const u16* qp = Q + (size_t)(qb + g * 16 + fm) * DM + h * DH + fq * 8;
    q0[g] = *(const bf16x8*)(qp);
    q1[g] = *(const bf16x8*)(qp + 32);
  }
  f32x4 o[2][4];
  float lsum[2] = {0.f, 0.f};
#pragma unroll
  for (int g = 0; g < 2; ++g)
#pragma unroll
    for (int c4 = 0; c4 < 4; ++c4)
#pragma unroll
      for (int r = 0; r < 4; ++r) o[g][c4][r] = 0.f;

  const int rr = tid >> 3;
  const int cc8 = (tid & 7) ^ (rr & 7);
  const u16* Kg0 = K + (size_t)rr * DM + h * DH + cc8 * 8;
  const u16* Kg1 = K + (size_t)(rr + 32) * DM + h * DH + cc8 * 8;
  const u16* Vg0 = Vt + (size_t)(h * DH + rr) * S_LEN + cc8 * 8;
  const u16* Vg1 = Vt + (size_t)(h * DH + rr + 32) * S_LEN + cc8 * 8;
  const int l0 = w * 512;
  const int l1 = 2048 + w * 512;
  const int sw7 = fm & 7;
  const f32x4 zf = {0.f, 0.f, 0.f, 0.f};

  glds16(Kg0, Ks + l0);
  glds16(Kg1, Ks + l1);
  glds16(Vg0, Vs + l0);
  glds16(Vg1, Vs + l1);

  int buf = 0;
  for (int kt = 0; kt < ntiles; ++kt) {
    __syncthreads();
    if (kt + 1 < ntiles) {
      int bo = (buf ^ 1) * 4096;
      size_t ko = (size_t)(kt + 1) * 64 * DM;
      int vo = (kt + 1) * 64;
      glds16(Kg0 + ko, Ks + bo + l0);
      glds16(Kg1 + ko, Ks + bo + l1);
      glds16(Vg0 + vo, Vs + bo + l0);
      glds16(Vg1 + vo, Vs + bo + l1);
    }
    const u16* Kb = Ks + buf * 4096;
    const u16* Vb = Vs + buf * 4096;

    // S^T = K * Q^T : D[key][q]; A = K-frag (shared across both q-groups)
    f32x4 st[2][4];
#pragma unroll
    for (int t = 0; t < 4; ++t) {
      const u16* kr = Kb + (t * 16 + fm) * 64;
      bf16x8 ka = *(const bf16x8*)(kr + ((fq ^ sw7) * 8));
      bf16x8 kb2 = *(const bf16x8*)(kr + (((fq + 4) ^ sw7) * 8));
#pragma unroll
      for (int g = 0; g < 2; ++g) {
        f32x4 s = __builtin_amdgcn_mfma_f32_16x16x32_bf16(ka, q0[g], zf, 0, 0, 0);
        st[g][t] = __builtin_amdgcn_mfma_f32_16x16x32_bf16(kb2, q1[g], s, 0, 0, 0);
      }
    }
    // causal mask: key = kt*64 + t*16 + fq*4 + r, q = qb + g*16 + fm
    if (kt >= dtile) {
#pragma unroll
      for (int g = 0; g < 2; ++g) {
        int qg = qb + g * 16 + fm;
#pragma unroll
        for (int t = 0; t < 4; ++t) {
          int key = kt * 64 + t * 16 + fq * 4;
#pragma unroll
          for (int r = 0; r < 4; ++r)
            st[g][t][r] = (key + r > qg) ? -1e30f : st[g][t][r];
        }
      }
    }
    // fixed-m softmax: p = exp2(s); accumulate per-lane lsum; P -> LDS packed
#pragma unroll
    for (int g = 0; g < 2; ++g) {
#pragma unroll
      for (int t = 0; t < 4; ++t) {
        float p0 = __builtin_amdgcn_exp2f(st[g][t][0]);
        float p1 = __builtin_amdgcn_exp2f(st[g][t][1]);
        float p2 = __builtin_amdgcn_exp2f(st[g][t][2]);
        float p3 = __builtin_amdgcn_exp2f(st[g][t][3]);
        lsum[g] += (p0 + p1) + (p2 + p3);
        ushort4 pk;
        pk.x = f2b(p0); pk.y = f2b(p1); pk.z = f2b(p2); pk.w = f2b(p3);
        *(ushort4*)(&Ps[w][g][fm * PSTR + t * 16 + fq * 4]) = pk;
      }
    }
    // V B-operand fragments (shared across q-groups)
    bf16x8 pvb[4][2];
#pragma unroll
    for (int c4 = 0; c4 < 4; ++c4) {
      const u16* vr = Vb + (c4 * 16 + fm) * 64;
      pvb[c4][0] = *(const bf16x8*)(vr + ((fq ^ sw7) * 8));
      pvb[c4][1] = *(const bf16x8*)(vr + (((fq + 4) ^ sw7) * 8));
    }
    asm volatile("s_waitcnt lgkmcnt(0)" ::: "memory");
#pragma unroll
    for (int g = 0; g < 2; ++g) {
      bf16x8 ap0 = *(const bf16x8*)(&Ps[w][g][fm * PSTR + fq * 8]);
      bf16x8 ap1 = *(const bf16x8*)(&Ps[w][g][fm * PSTR + 32 + fq * 8]);
#pragma unroll
      for (int c4 = 0; c4 < 4; ++c4) {
        o[g][c4] = __builtin_amdgcn_mfma_f32_16x16x32_bf16(ap0, pvb[c4][0], o[g][c4], 0, 0, 0);
        o[g][c4] = __builtin_amdgcn_mfma_f32_16x16x32_bf16(ap1, pvb[c4][1], o[g][c4], 0, 0, 0);
      }
    }
    buf ^= 1;
  }
  // final: reduce lsum across fq groups (lanes fm, fm+16, fm+32, fm+48)
#pragma unroll
  for (int g = 0; g < 2; ++g) {
    float lt = lsum[g];
    lt += __shfl_xor(lt, 16);
    lt += __shfl_xor(lt, 32);
    float il = 1.0f / lt;  // lane holds inv-l for q-row (qb + g*16 + fm)
    float ilr[4];
#pragma unroll
    for (int r = 0; r < 4; ++r) ilr[r] = __shfl(il, fq * 4 + r);
#pragma unroll
    for (int c4 = 0; c4 < 4; ++c4)
#pragma unroll
      for (int r = 0; r < 4; ++r) {
        int row = qb + g * 16 + fq * 4 + r;
        int col = h * DH + c4 * 16 + fm;
        Ctx[(size_t)row * DM + col] = f2b(o[g][c4][r] * ilr[r]);
      }
  }
}

extern "C" void kernel_launch(void* const* d_in, const int* in_sizes, int n_in,
                              void* d_out, int out_size, void* d_ws, size_t ws_size,
                              hipStream_t stream) {
  const float* x  = (const float*)d_in[0];
  const float* Wq = (const float*)d_in[1];
  const float* Wk = (const float*)d_in[2];
  const float* Wv = (const float*)d_in[3];
  const float* Wo = (const float*)d_in[4];
  float* out = (float*)d_out;

  const size_t MB = 1u << 20;
  char* ws = (char*)d_ws;
  u16* xb  = (u16*)(ws + 0 * MB);   // 8 MB
  u16* wqb = (u16*)(ws + 8 * MB);   // 2 MB
  u16* wkb = (u16*)(ws + 10 * MB);
  u16* wvb = (u16*)(ws + 12 * MB);
  u16* wob = (u16*)(ws + 14 * MB);
  u16* Qb  = (u16*)(ws + 16 * MB);  // 8 MB each
  u16* Kb  = (u16*)(ws + 24 * MB);
  u16* Vb  = (u16*)(ws + 32 * MB);
  u16* Vtb = (u16*)(ws + 40 * MB);
  u16* Ctx = (u16*)(ws + 48 * MB);

  cvt_all<<<8192, 256, 0, stream>>>(x, Wq, Wk, Wv, Wo, xb, wqb, wkb, wvb, wob);
  qkv_gemm<<<dim3(24, 32), 256, 0, stream>>>(xb, wqb, wkb, wvb, Qb, Kb, Vb);
  transpose_v<<<dim3(DM / 32, S_LEN / 32), dim3(32, 32), 0, stream>>>(Vb, Vtb);
  attn_kernel<<<dim3(S_LEN / 128, NH), 256, 0, stream>>>(Qb, Kb, Vtb, Ctx);
  o_gemm<<<dim3(DM / 128, S_LEN / 128), 256, 0, stream>>>(Ctx, wob, out, S_LEN, DM, DM);
}

// Round 4
// 258.741 us; speedup vs baseline: 2.0481x; 1.0798x over previous
//
#include <hip/hip_runtime.h>
#include <hip/hip_bf16.h>

typedef __attribute__((ext_vector_type(8))) short bf16x8;
typedef __attribute__((ext_vector_type(4))) float f32x4;
typedef unsigned short u16;

#define S_LEN 4096
#define DM 1024
#define NH 16
#define DH 64
#define PSTR 72

// manual RNE fp32->bf16 (inputs never NaN here): 3 VALU ops
__device__ __forceinline__ u16 f2b_rne(float f) {
  unsigned u = __builtin_bit_cast(unsigned, f);
  return (u16)((u + 0x7fffu + ((u >> 16) & 1u)) >> 16);
}
// pack two fp32 -> bf16x2 in one u32
__device__ __forceinline__ unsigned pk2(float a, float b) {
  unsigned ua = __builtin_bit_cast(unsigned, a);
  unsigned ub = __builtin_bit_cast(unsigned, b);
  ua = (ua + 0x7fffu + ((ua >> 16) & 1u)) >> 16;
  ub = (ub + 0x7fffu + ((ub >> 16) & 1u)) & 0xffff0000u;
  return ua | ub;
}

// global -> LDS direct (16B per lane; lds base must be wave-uniform)
__device__ __forceinline__ void glds16(const u16* g, u16* l) {
  __builtin_amdgcn_global_load_lds(
      (const __attribute__((address_space(1))) unsigned int*)g,
      (__attribute__((address_space(3))) unsigned int*)l, 16, 0, 0);
}

// ---------------- fp32 -> bf16, all 5 inputs in one launch ----------------
__global__ __launch_bounds__(256) void cvt_all(const float* __restrict__ x,
                                               const float* __restrict__ Wq,
                                               const float* __restrict__ Wk,
                                               const float* __restrict__ Wv,
                                               const float* __restrict__ Wo,
                                               u16* __restrict__ xb, u16* __restrict__ wqb,
                                               u16* __restrict__ wkb, u16* __restrict__ wvb,
                                               u16* __restrict__ wob) {
  int idx = (blockIdx.x * 256 + threadIdx.x) * 4;
  const float* src;
  u16* dst;
  int o;
  if (idx < 4194304) {
    src = x; dst = xb; o = idx;
  } else {
    int t = idx - 4194304;
    int wsel = t >> 20;
    o = t & 1048575;
    src = (wsel == 0) ? Wq : (wsel == 1) ? Wk : (wsel == 2) ? Wv : Wo;
    dst = (wsel == 0) ? wqb : (wsel == 1) ? wkb : (wsel == 2) ? wvb : wob;
  }
  float4 v = *(const float4*)(src + o);
  uint2 ov;
  ov.x = pk2(v.x, v.y);
  ov.y = pk2(v.z, v.w);
  *(uint2*)(dst + o) = ov;
}

// ---------------- zero the O/L accumulators (16 MB + 256 KB) ---------------
__global__ __launch_bounds__(256) void zero_kernel(float4* __restrict__ p) {
  p[blockIdx.x * 256 + threadIdx.x] = float4{0.f, 0.f, 0.f, 0.f};
}

// ---------------- fused QKV NT-GEMM with RoPE epilogue; V written transposed
// grid (24, 32): mat = bx>>3 (0=Q rope+scale, 1=K rope, 2=V -> Vt), nb = (bx&7)*128
__global__ __launch_bounds__(256) void qkv_gemm(const u16* __restrict__ A,
                                                const u16* __restrict__ Wq,
                                                const u16* __restrict__ Wk,
                                                const u16* __restrict__ Wv,
                                                u16* __restrict__ Qo, u16* __restrict__ Ko,
                                                u16* __restrict__ Vt) {
  __shared__ __align__(16) u16 As[2 * 128 * 32];
  __shared__ __align__(16) u16 Bs[2 * 128 * 32];
  const int mat = blockIdx.x >> 3;
  const u16* B = (mat == 0) ? Wq : (mat == 1) ? Wk : Wv;
  const int K = DM, N = DM;
  const int tid = threadIdx.x;
  const int wave = tid >> 6, lane = tid & 63;
  const int fm = lane & 15, fq = lane >> 4;
  const int mb = blockIdx.y * 128, nb = (blockIdx.x & 7) * 128;
  const int wm = (wave & 1) * 64, wn = (wave >> 1) * 64;

  f32x4 acc[4][4];
#pragma unroll
  for (int i = 0; i < 4; ++i)
#pragma unroll
    for (int j = 0; j < 4; ++j)
#pragma unroll
      for (int r = 0; r < 4; ++r) acc[i][j][r] = 0.f;

  const int r_ = tid >> 2;
  const int cg = (tid & 3) ^ ((r_ >> 1) & 3);
  const u16* Ag0 = A + (size_t)(mb + r_) * K + cg * 8;
  const u16* Ag1 = A + (size_t)(mb + r_ + 64) * K + cg * 8;
  const u16* Bg0 = B + (size_t)(nb + r_) * K + cg * 8;
  const u16* Bg1 = B + (size_t)(nb + r_ + 64) * K + cg * 8;
  const int l0 = wave * 512;
  const int l1 = 2048 + wave * 512;
  const int sw = (fm >> 1) & 3;

  int buf = 0;
  glds16(Ag0, As + l0);
  glds16(Ag1, As + l1);
  glds16(Bg0, Bs + l0);
  glds16(Bg1, Bs + l1);

  for (int k0 = 0; k0 < K; k0 += 32) {
    __syncthreads();
    if (k0 + 32 < K) {
      int bo = (buf ^ 1) * 4096;
      glds16(Ag0 + k0 + 32, As + bo + l0);
      glds16(Ag1 + k0 + 32, As + bo + l1);
      glds16(Bg0 + k0 + 32, Bs + bo + l0);
      glds16(Bg1 + k0 + 32, Bs + bo + l1);
    }
    const u16* Ab = As + buf * 4096;
    const u16* Bb = Bs + buf * 4096;
    bf16x8 av[4], bv[4];
#pragma unroll
    for (int t = 0; t < 4; ++t) {
      av[t] = *(const bf16x8*)(Ab + (wm + t * 16 + fm) * 32 + ((fq ^ sw) * 8));
      bv[t] = *(const bf16x8*)(Bb + (wn + t * 16 + fm) * 32 + ((fq ^ sw) * 8));
    }
#pragma unroll
    for (int i = 0; i < 4; ++i)
#pragma unroll
      for (int j = 0; j < 4; ++j)
        acc[i][j] = __builtin_amdgcn_mfma_f32_16x16x32_bf16(av[i], bv[j], acc[i][j], 0, 0, 0);
    buf ^= 1;
  }

  if (mat < 2) {
    // RoPE epilogue (in-register): pairs (d, d+32) = regs (j, j+2), d = j*16+fm, j in {0,1}
    u16* Out = (mat == 0) ? Qo : Ko;
    const float qs = (mat == 0) ? 0.1803368801111204f : 1.0f;  // 0.125*log2(e) for Q
    const float c1 = -9.2103403719761836f / 32.f;              // -ln(10000)/32
    const float if0 = __expf((float)fm * c1);
    const float if1 = __expf((float)(16 + fm) * c1);
#pragma unroll
    for (int ii = 0; ii < 4; ++ii) {
#pragma unroll
      for (int r = 0; r < 4; ++r) {
        float s = (float)(mb + wm + ii * 16 + fq * 4 + r);
#pragma unroll
        for (int jp = 0; jp < 2; ++jp) {
          float ang = s * (jp ? if1 : if0);
          float sn, cs;
          __sincosf(ang, &sn, &cs);
          float a = acc[ii][jp][r], b = acc[ii][jp + 2][r];
          acc[ii][jp][r] = (a * cs - b * sn) * qs;
          acc[ii][jp + 2][r] = (b * cs + a * sn) * qs;
        }
      }
    }
#pragma unroll
    for (int i = 0; i < 4; ++i)
#pragma unroll
      for (int j = 0; j < 4; ++j)
#pragma unroll
        for (int r = 0; r < 4; ++r) {
          int row = mb + wm + i * 16 + fq * 4 + r;
          int col = nb + wn + j * 16 + fm;
          Out[(size_t)row * N + col] = f2b_rne(acc[i][j][r]);
        }
  } else {
    // V: write transposed Vt[col][row]; 4 r-values are contiguous rows -> 8B store
#pragma unroll
    for (int i = 0; i < 4; ++i)
#pragma unroll
      for (int j = 0; j < 4; ++j) {
        int col = nb + wn + j * 16 + fm;
        int row0 = mb + wm + i * 16 + fq * 4;
        uint2 pv;
        pv.x = pk2(acc[i][j][0], acc[i][j][1]);
        pv.y = pk2(acc[i][j][2], acc[i][j][3]);
        *(uint2*)(Vt + (size_t)col * S_LEN + row0) = pv;
      }
  }
}

// ---------------- O-projection NT GEMM (fp32 out) ----------------
__global__ __launch_bounds__(256) void o_gemm(const u16* __restrict__ A,
                                              const u16* __restrict__ B,
                                              float* __restrict__ C, int M, int N, int K) {
  __shared__ __align__(16) u16 As[2 * 128 * 32];
  __shared__ __align__(16) u16 Bs[2 * 128 * 32];
  const int tid = threadIdx.x;
  const int wave = tid >> 6, lane = tid & 63;
  const int fm = lane & 15, fq = lane >> 4;
  const int mb = blockIdx.y * 128, nb = blockIdx.x * 128;
  const int wm = (wave & 1) * 64, wn = (wave >> 1) * 64;

  f32x4 acc[4][4];
#pragma unroll
  for (int i = 0; i < 4; ++i)
#pragma unroll
    for (int j = 0; j < 4; ++j)
#pragma unroll
      for (int r = 0; r < 4; ++r) acc[i][j][r] = 0.f;

  const int r_ = tid >> 2;
  const int cg = (tid & 3) ^ ((r_ >> 1) & 3);
  const u16* Ag0 = A + (size_t)(mb + r_) * K + cg * 8;
  const u16* Ag1 = A + (size_t)(mb + r_ + 64) * K + cg * 8;
  const u16* Bg0 = B + (size_t)(nb + r_) * K + cg * 8;
  const u16* Bg1 = B + (size_t)(nb + r_ + 64) * K + cg * 8;
  const int l0 = wave * 512;
  const int l1 = 2048 + wave * 512;
  const int sw = (fm >> 1) & 3;

  int buf = 0;
  glds16(Ag0, As + l0);
  glds16(Ag1, As + l1);
  glds16(Bg0, Bs + l0);
  glds16(Bg1, Bs + l1);

  for (int k0 = 0; k0 < K; k0 += 32) {
    __syncthreads();
    if (k0 + 32 < K) {
      int bo = (buf ^ 1) * 4096;
      glds16(Ag0 + k0 + 32, As + bo + l0);
      glds16(Ag1 + k0 + 32, As + bo + l1);
      glds16(Bg0 + k0 + 32, Bs + bo + l0);
      glds16(Bg1 + k0 + 32, Bs + bo + l1);
    }
    const u16* Ab = As + buf * 4096;
    const u16* Bb = Bs + buf * 4096;
    bf16x8 av[4], bv[4];
#pragma unroll
    for (int t = 0; t < 4; ++t) {
      av[t] = *(const bf16x8*)(Ab + (wm + t * 16 + fm) * 32 + ((fq ^ sw) * 8));
      bv[t] = *(const bf16x8*)(Bb + (wn + t * 16 + fm) * 32 + ((fq ^ sw) * 8));
    }
#pragma unroll
    for (int i = 0; i < 4; ++i)
#pragma unroll
      for (int j = 0; j < 4; ++j)
        acc[i][j] = __builtin_amdgcn_mfma_f32_16x16x32_bf16(av[i], bv[j], acc[i][j], 0, 0, 0);
    buf ^= 1;
  }
#pragma unroll
  for (int i = 0; i < 4; ++i)
#pragma unroll
    for (int j = 0; j < 4; ++j)
#pragma unroll
      for (int r = 0; r < 4; ++r) {
        int row = mb + wm + i * 16 + fq * 4 + r;
        int col = nb + wn + j * 16 + fm;
        C[(size_t)row * N + col] = acc[i][j][r];
      }
}

// ---------------- causal flash attention v4: split-K + atomic combine -------
// grid (64, 16): qt = 31-(bx>>1) (big first), half = bx&1.
// Block handles q rows [qt*128, qt*128+128), k-tiles [half*(qt+1), (half+1)*(qt+1)).
// Fixed-m (m=0) exp2 softmax -> partials additive: unnormalized O and lsum
// accumulate into global fp32 via HW atomics; combine kernel normalizes.
__global__ __launch_bounds__(256) void attn_kernel(const u16* __restrict__ Q,
                                                   const u16* __restrict__ K,
                                                   const u16* __restrict__ Vt,
                                                   float* __restrict__ Oacc,
                                                   float* __restrict__ Lacc) {
  __shared__ __align__(16) u16 Ks[2 * 64 * 64];
  __shared__ __align__(16) u16 Vs[2 * 64 * 64];
  __shared__ __align__(16) u16 Ps[4][2][16 * PSTR];
  const int tid = threadIdx.x;
  const int w = tid >> 6, lane = tid & 63;
  const int fm = lane & 15, fq = lane >> 4;
  const int qt = 31 - (blockIdx.x >> 1);
  const int half = blockIdx.x & 1;
  const int h = blockIdx.y;
  const int qb = qt * 128 + w * 32;
  const int nlocal = qt + 1;
  const int kbase = half * nlocal;
  const int dtile = qb >> 6;  // tile == dtile: partial mask; > dtile: fully masked

  bf16x8 q0[2], q1[2];
#pragma unroll
  for (int g = 0; g < 2; ++g) {
    const u16* qp = Q + (size_t)(qb + g * 16 + fm) * DM + h * DH + fq * 8;
    q0[g] = *(const bf16x8*)(qp);
    q1[g] = *(const bf16x8*)(qp + 32);
  }
  f32x4 o[2][4];
  float lsum[2] = {0.f, 0.f};
#pragma unroll
  for (int g = 0; g < 2; ++g)
#pragma unroll
    for (int c4 = 0; c4 < 4; ++c4)
#pragma unroll
      for (int r = 0; r < 4; ++r) o[g][c4][r] = 0.f;

  const int rr = tid >> 3;
  const int cc8 = (tid & 7) ^ (rr & 7);
  const u16* Kg0 = K + (size_t)rr * DM + h * DH + cc8 * 8;
  const u16* Kg1 = K + (size_t)(rr + 32) * DM + h * DH + cc8 * 8;
  const u16* Vg0 = Vt + (size_t)(h * DH + rr) * S_LEN + cc8 * 8;
  const u16* Vg1 = Vt + (size_t)(h * DH + rr + 32) * S_LEN + cc8 * 8;
  const int l0 = w * 512;
  const int l1 = 2048 + w * 512;
  const int sw7 = fm & 7;
  const f32x4 zf = {0.f, 0.f, 0.f, 0.f};

  {
    size_t ko = (size_t)kbase * 64 * DM;
    int vo = kbase * 64;
    glds16(Kg0 + ko, Ks + l0);
    glds16(Kg1 + ko, Ks + l1);
    glds16(Vg0 + vo, Vs + l0);
    glds16(Vg1 + vo, Vs + l1);
  }

  int buf = 0;
  for (int kl = 0; kl < nlocal; ++kl) {
    const int ktg = kbase + kl;
    __syncthreads();
    if (kl + 1 < nlocal) {
      int bo = (buf ^ 1) * 4096;
      size_t ko = (size_t)(ktg + 1) * 64 * DM;
      int vo = (ktg + 1) * 64;
      glds16(Kg0 + ko, Ks + bo + l0);
      glds16(Kg1 + ko, Ks + bo + l1);
      glds16(Vg0 + vo, Vs + bo + l0);
      glds16(Vg1 + vo, Vs + bo + l1);
    }
    if (ktg <= dtile) {  // skip fully-masked tiles (wave-uniform branch)
      const u16* Kb = Ks + buf * 4096;
      const u16* Vb = Vs + buf * 4096;

      // S^T = K * Q^T : D[key][q]
      f32x4 st[2][4];
#pragma unroll
      for (int t = 0; t < 4; ++t) {
        const u16* kr = Kb + (t * 16 + fm) * 64;
        bf16x8 ka = *(const bf16x8*)(kr + ((fq ^ sw7) * 8));
        bf16x8 kb2 = *(const bf16x8*)(kr + (((fq + 4) ^ sw7) * 8));
#pragma unroll
        for (int g = 0; g < 2; ++g) {
          f32x4 s = __builtin_amdgcn_mfma_f32_16x16x32_bf16(ka, q0[g], zf, 0, 0, 0);
          st[g][t] = __builtin_amdgcn_mfma_f32_16x16x32_bf16(kb2, q1[g], s, 0, 0, 0);
        }
      }
      if (ktg == dtile) {  // diagonal tile: partial causal mask
#pragma unroll
        for (int g = 0; g < 2; ++g) {
          int qg = qb + g * 16 + fm;
#pragma unroll
          for (int t = 0; t < 4; ++t) {
            int key = ktg * 64 + t * 16 + fq * 4;
#pragma unroll
            for (int r = 0; r < 4; ++r)
              st[g][t][r] = (key + r > qg) ? -1e30f : st[g][t][r];
          }
        }
      }
      // fixed-m softmax: p = exp2(s); per-lane lsum; P -> LDS packed (b64)
#pragma unroll
      for (int g = 0; g < 2; ++g) {
#pragma unroll
        for (int t = 0; t < 4; ++t) {
          float p0 = __builtin_amdgcn_exp2f(st[g][t][0]);
          float p1 = __builtin_amdgcn_exp2f(st[g][t][1]);
          float p2 = __builtin_amdgcn_exp2f(st[g][t][2]);
          float p3 = __builtin_amdgcn_exp2f(st[g][t][3]);
          lsum[g] += (p0 + p1) + (p2 + p3);
          uint2 pk;
          pk.x = pk2(p0, p1);
          pk.y = pk2(p2, p3);
          *(uint2*)(&Ps[w][g][fm * PSTR + t * 16 + fq * 4]) = pk;
        }
      }
      bf16x8 pvb[4][2];
#pragma unroll
      for (int c4 = 0; c4 < 4; ++c4) {
        const u16* vr = Vb + (c4 * 16 + fm) * 64;
        pvb[c4][0] = *(const bf16x8*)(vr + ((fq ^ sw7) * 8));
        pvb[c4][1] = *(const bf16x8*)(vr + (((fq + 4) ^ sw7) * 8));
      }
      asm volatile("s_waitcnt lgkmcnt(0)" ::: "memory");
#pragma unroll
      for (int g = 0; g < 2; ++g) {
        bf16x8 ap0 = *(const bf16x8*)(&Ps[w][g][fm * PSTR + fq * 8]);
        bf16x8 ap1 = *(const bf16x8*)(&Ps[w][g][fm * PSTR + 32 + fq * 8]);
#pragma unroll
        for (int c4 = 0; c4 < 4; ++c4) {
          o[g][c4] = __builtin_amdgcn_mfma_f32_16x16x32_bf16(ap0, pvb[c4][0], o[g][c4], 0, 0, 0);
          o[g][c4] = __builtin_amdgcn_mfma_f32_16x16x32_bf16(ap1, pvb[c4][1], o[g][c4], 0, 0, 0);
        }
      }
    }
    buf ^= 1;
  }
  // accumulate partials: Oacc[h][row][d], Lacc[h][row]
  float* Ob = Oacc + ((size_t)h * S_LEN + qt * 128 + w * 32) * DH;
  float* Lb = Lacc + h * S_LEN + qt * 128 + w * 32;
#pragma unroll
  for (int g = 0; g < 2; ++g) {
    float lt = lsum[g];
    lt += __shfl_xor(lt, 16);
    lt += __shfl_xor(lt, 32);
    if (fq == 0) unsafeAtomicAdd(Lb + g * 16 + fm, lt);
#pragma unroll
    for (int c4 = 0; c4 < 4; ++c4)
#pragma unroll
      for (int r = 0; r < 4; ++r)
        unsafeAtomicAdd(Ob + (g * 16 + fq * 4 + r) * DH + c4 * 16 + fm, o[g][c4][r]);
  }
}

// ---------------- combine: Ctx = bf16(Oacc / Lacc) --------------------------
__global__ __launch_bounds__(256) void combine_kernel(const float* __restrict__ Oacc,
                                                      const float* __restrict__ Lacc,
                                                      u16* __restrict__ Ctx) {
  int idx = blockIdx.x * 256 + threadIdx.x;  // 1,048,576 threads
  int d4 = (idx & 15) * 4;
  int hh = (idx >> 4) & 15;
  int row = idx >> 8;
  float4 a = *(const float4*)(Oacc + ((size_t)hh * S_LEN + row) * DH + d4);
  float il = 1.0f / Lacc[hh * S_LEN + row];
  uint2 o;
  o.x = pk2(a.x * il, a.y * il);
  o.y = pk2(a.z * il, a.w * il);
  *(uint2*)(Ctx + (size_t)row * DM + hh * DH + d4) = o;
}

extern "C" void kernel_launch(void* const* d_in, const int* in_sizes, int n_in,
                              void* d_out, int out_size, void* d_ws, size_t ws_size,
                              hipStream_t stream) {
  const float* x  = (const float*)d_in[0];
  const float* Wq = (const float*)d_in[1];
  const float* Wk = (const float*)d_in[2];
  const float* Wv = (const float*)d_in[3];
  const float* Wo = (const float*)d_in[4];
  float* out = (float*)d_out;

  const size_t MB = 1u << 20;
  char* ws = (char*)d_ws;
  // region [0, 16.25 MB): phase 1 = xb(8) + wqb/wkb/wvb(2+2+2); phase 2 = Oacc(16)+Lacc(0.25)
  u16* xb    = (u16*)(ws + 0 * MB);
  u16* wqb   = (u16*)(ws + 8 * MB);
  u16* wkb   = (u16*)(ws + 10 * MB);
  u16* wvb   = (u16*)(ws + 12 * MB);
  float* Oacc = (float*)(ws + 0 * MB);
  float* Lacc = (float*)(ws + 16 * MB);
  u16* wob   = (u16*)(ws + 17 * MB);  // persists to o_gemm
  u16* Qb    = (u16*)(ws + 19 * MB);
  u16* Kb    = (u16*)(ws + 27 * MB);
  u16* Vtb   = (u16*)(ws + 35 * MB);
  u16* Ctx   = (u16*)(ws + 43 * MB);

  cvt_all<<<8192, 256, 0, stream>>>(x, Wq, Wk, Wv, Wo, xb, wqb, wkb, wvb, wob);
  qkv_gemm<<<dim3(24, 32), 256, 0, stream>>>(xb, wqb, wkb, wvb, Qb, Kb, Vtb);
  zero_kernel<<<4160, 256, 0, stream>>>((float4*)Oacc);  // zeros Oacc+Lacc (16.25 MB)
  attn_kernel<<<dim3(64, NH), 256, 0, stream>>>(Qb, Kb, Vtb, Oacc, Lacc);
  combine_kernel<<<4096, 256, 0, stream>>>(Oacc, Lacc, Ctx);
  o_gemm<<<dim3(DM / 128, S_LEN / 128), 256, 0, stream>>>(Ctx, wob, out, S_LEN, DM, DM);
}

// Round 5
// 245.830 us; speedup vs baseline: 2.1556x; 1.0525x over previous
//
#include <hip/hip_runtime.h>
#include <hip/hip_bf16.h>

typedef __attribute__((ext_vector_type(8))) short bf16x8;
typedef __attribute__((ext_vector_type(4))) float f32x4;
typedef unsigned short u16;

#define S_LEN 4096
#define DM 1024
#define NH 16
#define DH 64
#define PSTR 72

// manual RNE fp32->bf16 (inputs never NaN here): 3 VALU ops
__device__ __forceinline__ u16 f2b_rne(float f) {
  unsigned u = __builtin_bit_cast(unsigned, f);
  return (u16)((u + 0x7fffu + ((u >> 16) & 1u)) >> 16);
}
// pack two fp32 -> bf16x2 in one u32 (RNE)
__device__ __forceinline__ unsigned pk2(float a, float b) {
  unsigned ua = __builtin_bit_cast(unsigned, a);
  unsigned ub = __builtin_bit_cast(unsigned, b);
  ua = (ua + 0x7fffu + ((ua >> 16) & 1u)) >> 16;
  ub = (ub + 0x7fffu + ((ub >> 16) & 1u)) & 0xffff0000u;
  return ua | ub;
}
// pack two fp32 -> bf16x2, TRUNCATED: single v_perm_b32.
// bias cancels in softmax (same P in numerator and denominator).
__device__ __forceinline__ unsigned pk2t(float a, float b) {
  return __builtin_amdgcn_perm(__builtin_bit_cast(unsigned, b),
                               __builtin_bit_cast(unsigned, a), 0x07060302u);
}

// global -> LDS direct (16B per lane; lds base must be wave-uniform)
__device__ __forceinline__ void glds16(const u16* g, u16* l) {
  __builtin_amdgcn_global_load_lds(
      (const __attribute__((address_space(1))) unsigned int*)g,
      (__attribute__((address_space(3))) unsigned int*)l, 16, 0, 0);
}

// ---------------- fp32 -> bf16, all 5 inputs in one launch ----------------
__global__ __launch_bounds__(256) void cvt_all(const float* __restrict__ x,
                                               const float* __restrict__ Wq,
                                               const float* __restrict__ Wk,
                                               const float* __restrict__ Wv,
                                               const float* __restrict__ Wo,
                                               u16* __restrict__ xb, u16* __restrict__ wqb,
                                               u16* __restrict__ wkb, u16* __restrict__ wvb,
                                               u16* __restrict__ wob) {
  int idx = (blockIdx.x * 256 + threadIdx.x) * 4;
  const float* src;
  u16* dst;
  int o;
  if (idx < 4194304) {
    src = x; dst = xb; o = idx;
  } else {
    int t = idx - 4194304;
    int wsel = t >> 20;
    o = t & 1048575;
    src = (wsel == 0) ? Wq : (wsel == 1) ? Wk : (wsel == 2) ? Wv : Wo;
    dst = (wsel == 0) ? wqb : (wsel == 1) ? wkb : (wsel == 2) ? wvb : wob;
  }
  float4 v = *(const float4*)(src + o);
  uint2 ov;
  ov.x = pk2(v.x, v.y);
  ov.y = pk2(v.z, v.w);
  *(uint2*)(dst + o) = ov;
}

// ---------------- zero the O/L accumulators (16 MB + 256 KB) ---------------
__global__ __launch_bounds__(256) void zero_kernel(float4* __restrict__ p) {
  p[blockIdx.x * 256 + threadIdx.x] = float4{0.f, 0.f, 0.f, 0.f};
}

// ---------------- fused QKV NT-GEMM with RoPE epilogue; V written transposed
// grid (24, 32): mat = bx>>3 (0=Q rope+scale, 1=K rope, 2=V -> Vt), nb = (bx&7)*128
__global__ __launch_bounds__(256) void qkv_gemm(const u16* __restrict__ A,
                                                const u16* __restrict__ Wq,
                                                const u16* __restrict__ Wk,
                                                const u16* __restrict__ Wv,
                                                u16* __restrict__ Qo, u16* __restrict__ Ko,
                                                u16* __restrict__ Vt) {
  __shared__ __align__(16) u16 As[2 * 128 * 32];
  __shared__ __align__(16) u16 Bs[2 * 128 * 32];
  const int mat = blockIdx.x >> 3;
  const u16* B = (mat == 0) ? Wq : (mat == 1) ? Wk : Wv;
  const int K = DM, N = DM;
  const int tid = threadIdx.x;
  const int wave = tid >> 6, lane = tid & 63;
  const int fm = lane & 15, fq = lane >> 4;
  const int mb = blockIdx.y * 128, nb = (blockIdx.x & 7) * 128;
  const int wm = (wave & 1) * 64, wn = (wave >> 1) * 64;

  f32x4 acc[4][4];
#pragma unroll
  for (int i = 0; i < 4; ++i)
#pragma unroll
    for (int j = 0; j < 4; ++j)
#pragma unroll
      for (int r = 0; r < 4; ++r) acc[i][j][r] = 0.f;

  const int r_ = tid >> 2;
  const int cg = (tid & 3) ^ ((r_ >> 1) & 3);
  const u16* Ag0 = A + (size_t)(mb + r_) * K + cg * 8;
  const u16* Ag1 = A + (size_t)(mb + r_ + 64) * K + cg * 8;
  const u16* Bg0 = B + (size_t)(nb + r_) * K + cg * 8;
  const u16* Bg1 = B + (size_t)(nb + r_ + 64) * K + cg * 8;
  const int l0 = wave * 512;
  const int l1 = 2048 + wave * 512;
  const int sw = (fm >> 1) & 3;

  int buf = 0;
  glds16(Ag0, As + l0);
  glds16(Ag1, As + l1);
  glds16(Bg0, Bs + l0);
  glds16(Bg1, Bs + l1);

  for (int k0 = 0; k0 < K; k0 += 32) {
    __syncthreads();
    if (k0 + 32 < K) {
      int bo = (buf ^ 1) * 4096;
      glds16(Ag0 + k0 + 32, As + bo + l0);
      glds16(Ag1 + k0 + 32, As + bo + l1);
      glds16(Bg0 + k0 + 32, Bs + bo + l0);
      glds16(Bg1 + k0 + 32, Bs + bo + l1);
    }
    const u16* Ab = As + buf * 4096;
    const u16* Bb = Bs + buf * 4096;
    bf16x8 av[4], bv[4];
#pragma unroll
    for (int t = 0; t < 4; ++t) {
      av[t] = *(const bf16x8*)(Ab + (wm + t * 16 + fm) * 32 + ((fq ^ sw) * 8));
      bv[t] = *(const bf16x8*)(Bb + (wn + t * 16 + fm) * 32 + ((fq ^ sw) * 8));
    }
#pragma unroll
    for (int i = 0; i < 4; ++i)
#pragma unroll
      for (int j = 0; j < 4; ++j)
        acc[i][j] = __builtin_amdgcn_mfma_f32_16x16x32_bf16(av[i], bv[j], acc[i][j], 0, 0, 0);
    buf ^= 1;
  }

  if (mat < 2) {
    // RoPE epilogue (in-register): pairs (d, d+32) = regs (j, j+2), d = j*16+fm, j in {0,1}
    u16* Out = (mat == 0) ? Qo : Ko;
    const float qs = (mat == 0) ? 0.1803368801111204f : 1.0f;  // 0.125*log2(e) for Q
    const float c1 = -9.2103403719761836f / 32.f;              // -ln(10000)/32
    const float if0 = __expf((float)fm * c1);
    const float if1 = __expf((float)(16 + fm) * c1);
#pragma unroll
    for (int ii = 0; ii < 4; ++ii) {
#pragma unroll
      for (int r = 0; r < 4; ++r) {
        float s = (float)(mb + wm + ii * 16 + fq * 4 + r);
#pragma unroll
        for (int jp = 0; jp < 2; ++jp) {
          float ang = s * (jp ? if1 : if0);
          float sn, cs;
          __sincosf(ang, &sn, &cs);
          float a = acc[ii][jp][r], b = acc[ii][jp + 2][r];
          acc[ii][jp][r] = (a * cs - b * sn) * qs;
          acc[ii][jp + 2][r] = (b * cs + a * sn) * qs;
        }
      }
    }
#pragma unroll
    for (int i = 0; i < 4; ++i)
#pragma unroll
      for (int j = 0; j < 4; ++j)
#pragma unroll
        for (int r = 0; r < 4; ++r) {
          int row = mb + wm + i * 16 + fq * 4 + r;
          int col = nb + wn + j * 16 + fm;
          Out[(size_t)row * N + col] = f2b_rne(acc[i][j][r]);
        }
  } else {
    // V: write transposed Vt[col][row]; 4 r-values are contiguous rows -> 8B store
#pragma unroll
    for (int i = 0; i < 4; ++i)
#pragma unroll
      for (int j = 0; j < 4; ++j) {
        int col = nb + wn + j * 16 + fm;
        int row0 = mb + wm + i * 16 + fq * 4;
        uint2 pv;
        pv.x = pk2(acc[i][j][0], acc[i][j][1]);
        pv.y = pk2(acc[i][j][2], acc[i][j][3]);
        *(uint2*)(Vt + (size_t)col * S_LEN + row0) = pv;
      }
  }
}

// ---------------- O-projection NT GEMM (fp32 out) ----------------
__global__ __launch_bounds__(256) void o_gemm(const u16* __restrict__ A,
                                              const u16* __restrict__ B,
                                              float* __restrict__ C, int M, int N, int K) {
  __shared__ __align__(16) u16 As[2 * 128 * 32];
  __shared__ __align__(16) u16 Bs[2 * 128 * 32];
  const int tid = threadIdx.x;
  const int wave = tid >> 6, lane = tid & 63;
  const int fm = lane & 15, fq = lane >> 4;
  const int mb = blockIdx.y * 128, nb = blockIdx.x * 128;
  const int wm = (wave & 1) * 64, wn = (wave >> 1) * 64;

  f32x4 acc[4][4];
#pragma unroll
  for (int i = 0; i < 4; ++i)
#pragma unroll
    for (int j = 0; j < 4; ++j)
#pragma unroll
      for (int r = 0; r < 4; ++r) acc[i][j][r] = 0.f;

  const int r_ = tid >> 2;
  const int cg = (tid & 3) ^ ((r_ >> 1) & 3);
  const u16* Ag0 = A + (size_t)(mb + r_) * K + cg * 8;
  const u16* Ag1 = A + (size_t)(mb + r_ + 64) * K + cg * 8;
  const u16* Bg0 = B + (size_t)(nb + r_) * K + cg * 8;
  const u16* Bg1 = B + (size_t)(nb + r_ + 64) * K + cg * 8;
  const int l0 = wave * 512;
  const int l1 = 2048 + wave * 512;
  const int sw = (fm >> 1) & 3;

  int buf = 0;
  glds16(Ag0, As + l0);
  glds16(Ag1, As + l1);
  glds16(Bg0, Bs + l0);
  glds16(Bg1, Bs + l1);

  for (int k0 = 0; k0 < K; k0 += 32) {
    __syncthreads();
    if (k0 + 32 < K) {
      int bo = (buf ^ 1) * 4096;
      glds16(Ag0 + k0 + 32, As + bo + l0);
      glds16(Ag1 + k0 + 32, As + bo + l1);
      glds16(Bg0 + k0 + 32, Bs + bo + l0);
      glds16(Bg1 + k0 + 32, Bs + bo + l1);
    }
    const u16* Ab = As + buf * 4096;
    const u16* Bb = Bs + buf * 4096;
    bf16x8 av[4], bv[4];
#pragma unroll
    for (int t = 0; t < 4; ++t) {
      av[t] = *(const bf16x8*)(Ab + (wm + t * 16 + fm) * 32 + ((fq ^ sw) * 8));
      bv[t] = *(const bf16x8*)(Bb + (wn + t * 16 + fm) * 32 + ((fq ^ sw) * 8));
    }
#pragma unroll
    for (int i = 0; i < 4; ++i)
#pragma unroll
      for (int j = 0; j < 4; ++j)
        acc[i][j] = __builtin_amdgcn_mfma_f32_16x16x32_bf16(av[i], bv[j], acc[i][j], 0, 0, 0);
    buf ^= 1;
  }
#pragma unroll
  for (int i = 0; i < 4; ++i)
#pragma unroll
    for (int j = 0; j < 4; ++j)
#pragma unroll
      for (int r = 0; r < 4; ++r) {
        int row = mb + wm + i * 16 + fq * 4 + r;
        int col = nb + wn + j * 16 + fm;
        C[(size_t)row * N + col] = acc[i][j][r];
      }
}

// ---------------- causal flash attention v5: VALU diet ----------------------
// Split-K (grid (64,16)) + fixed-m exp2 softmax. New: P packed via v_perm_b32
// (truncation, bias cancels in softmax); lsum computed by ones-MFMA on the
// idle matrix pipe (C-layout rows match O accumulator rows).
__global__ __launch_bounds__(256) void attn_kernel(const u16* __restrict__ Q,
                                                   const u16* __restrict__ K,
                                                   const u16* __restrict__ Vt,
                                                   float* __restrict__ Oacc,
                                                   float* __restrict__ Lacc) {
  __shared__ __align__(16) u16 Ks[2 * 64 * 64];
  __shared__ __align__(16) u16 Vs[2 * 64 * 64];
  __shared__ __align__(16) u16 Ps[4][2][16 * PSTR];
  const int tid = threadIdx.x;
  const int w = tid >> 6, lane = tid & 63;
  const int fm = lane & 15, fq = lane >> 4;
  const int qt = 31 - (blockIdx.x >> 1);
  const int half = blockIdx.x & 1;
  const int h = blockIdx.y;
  const int qb = qt * 128 + w * 32;
  const int nlocal = qt + 1;
  const int kbase = half * nlocal;
  const int dtile = qb >> 6;  // tile == dtile: partial mask; > dtile: fully masked

  bf16x8 q0[2], q1[2];
#pragma unroll
  for (int g = 0; g < 2; ++g) {
    const u16* qp = Q + (size_t)(qb + g * 16 + fm) * DM + h * DH + fq * 8;
    q0[g] = *(const bf16x8*)(qp);
    q1[g] = *(const bf16x8*)(qp + 32);
  }
  f32x4 o[2][4];
  f32x4 ls[2];  // lsum accumulator via ones-MFMA; rows = fq*4+r (match o rows)
#pragma unroll
  for (int g = 0; g < 2; ++g) {
#pragma unroll
    for (int r = 0; r < 4; ++r) ls[g][r] = 0.f;
#pragma unroll
    for (int c4 = 0; c4 < 4; ++c4)
#pragma unroll
      for (int r = 0; r < 4; ++r) o[g][c4][r] = 0.f;
  }
  const short ONEB = (short)0x3F80;  // 1.0 bf16
  const bf16x8 vone = {ONEB, ONEB, ONEB, ONEB, ONEB, ONEB, ONEB, ONEB};

  const int rr = tid >> 3;
  const int cc8 = (tid & 7) ^ (rr & 7);
  const u16* Kg0 = K + (size_t)rr * DM + h * DH + cc8 * 8;
  const u16* Kg1 = K + (size_t)(rr + 32) * DM + h * DH + cc8 * 8;
  const u16* Vg0 = Vt + (size_t)(h * DH + rr) * S_LEN + cc8 * 8;
  const u16* Vg1 = Vt + (size_t)(h * DH + rr + 32) * S_LEN + cc8 * 8;
  const int l0 = w * 512;
  const int l1 = 2048 + w * 512;
  const int sw7 = fm & 7;
  const f32x4 zf = {0.f, 0.f, 0.f, 0.f};

  {
    size_t ko = (size_t)kbase * 64 * DM;
    int vo = kbase * 64;
    glds16(Kg0 + ko, Ks + l0);
    glds16(Kg1 + ko, Ks + l1);
    glds16(Vg0 + vo, Vs + l0);
    glds16(Vg1 + vo, Vs + l1);
  }

  int buf = 0;
  for (int kl = 0; kl < nlocal; ++kl) {
    const int ktg = kbase + kl;
    __syncthreads();
    if (kl + 1 < nlocal) {
      int bo = (buf ^ 1) * 4096;
      size_t ko = (size_t)(ktg + 1) * 64 * DM;
      int vo = (ktg + 1) * 64;
      glds16(Kg0 + ko, Ks + bo + l0);
      glds16(Kg1 + ko, Ks + bo + l1);
      glds16(Vg0 + vo, Vs + bo + l0);
      glds16(Vg1 + vo, Vs + bo + l1);
    }
    if (ktg <= dtile) {  // skip fully-masked tiles (wave-uniform branch)
      const u16* Kb = Ks + buf * 4096;
      const u16* Vb = Vs + buf * 4096;

      // S^T = K * Q^T : D[key][q]
      f32x4 st[2][4];
#pragma unroll
      for (int t = 0; t < 4; ++t) {
        const u16* kr = Kb + (t * 16 + fm) * 64;
        bf16x8 ka = *(const bf16x8*)(kr + ((fq ^ sw7) * 8));
        bf16x8 kb2 = *(const bf16x8*)(kr + (((fq + 4) ^ sw7) * 8));
#pragma unroll
        for (int g = 0; g < 2; ++g) {
          f32x4 s = __builtin_amdgcn_mfma_f32_16x16x32_bf16(ka, q0[g], zf, 0, 0, 0);
          st[g][t] = __builtin_amdgcn_mfma_f32_16x16x32_bf16(kb2, q1[g], s, 0, 0, 0);
        }
      }
      if (ktg == dtile) {  // diagonal tile: partial causal mask
#pragma unroll
        for (int g = 0; g < 2; ++g) {
          int qg = qb + g * 16 + fm;
#pragma unroll
          for (int t = 0; t < 4; ++t) {
            int key = ktg * 64 + t * 16 + fq * 4;
#pragma unroll
            for (int r = 0; r < 4; ++r)
              st[g][t][r] = (key + r > qg) ? -1e30f : st[g][t][r];
          }
        }
      }
      // fixed-m softmax: p = exp2(s); P -> LDS via single-instr truncating pack
#pragma unroll
      for (int g = 0; g < 2; ++g) {
#pragma unroll
        for (int t = 0; t < 4; ++t) {
          float p0 = __builtin_amdgcn_exp2f(st[g][t][0]);
          float p1 = __builtin_amdgcn_exp2f(st[g][t][1]);
          float p2 = __builtin_amdgcn_exp2f(st[g][t][2]);
          float p3 = __builtin_amdgcn_exp2f(st[g][t][3]);
          uint2 pk;
          pk.x = pk2t(p0, p1);
          pk.y = pk2t(p2, p3);
          *(uint2*)(&Ps[w][g][fm * PSTR + t * 16 + fq * 4]) = pk;
        }
      }
      bf16x8 pvb[4][2];
#pragma unroll
      for (int c4 = 0; c4 < 4; ++c4) {
        const u16* vr = Vb + (c4 * 16 + fm) * 64;
        pvb[c4][0] = *(const bf16x8*)(vr + ((fq ^ sw7) * 8));
        pvb[c4][1] = *(const bf16x8*)(vr + (((fq + 4) ^ sw7) * 8));
      }
      asm volatile("s_waitcnt lgkmcnt(0)" ::: "memory");
#pragma unroll
      for (int g = 0; g < 2; ++g) {
        bf16x8 ap0 = *(const bf16x8*)(&Ps[w][g][fm * PSTR + fq * 8]);
        bf16x8 ap1 = *(const bf16x8*)(&Ps[w][g][fm * PSTR + 32 + fq * 8]);
        // lsum via ones-MFMA (matrix pipe has ~8x headroom vs VALU)
        ls[g] = __builtin_amdgcn_mfma_f32_16x16x32_bf16(ap0, vone, ls[g], 0, 0, 0);
        ls[g] = __builtin_amdgcn_mfma_f32_16x16x32_bf16(ap1, vone, ls[g], 0, 0, 0);
#pragma unroll
        for (int c4 = 0; c4 < 4; ++c4) {
          o[g][c4] = __builtin_amdgcn_mfma_f32_16x16x32_bf16(ap0, pvb[c4][0], o[g][c4], 0, 0, 0);
          o[g][c4] = __builtin_amdgcn_mfma_f32_16x16x32_bf16(ap1, pvb[c4][1], o[g][c4], 0, 0, 0);
        }
      }
    }
    buf ^= 1;
  }
  // accumulate partials: Oacc[h][row][d], Lacc[h][row]; ls rows = o rows = fq*4+r
  float* Ob = Oacc + ((size_t)h * S_LEN + qt * 128 + w * 32) * DH;
  float* Lb = Lacc + h * S_LEN + qt * 128 + w * 32;
#pragma unroll
  for (int g = 0; g < 2; ++g) {
    if (fm == 0) {
#pragma unroll
      for (int r = 0; r < 4; ++r)
        unsafeAtomicAdd(Lb + g * 16 + fq * 4 + r, ls[g][r]);
    }
#pragma unroll
    for (int c4 = 0; c4 < 4; ++c4)
#pragma unroll
      for (int r = 0; r < 4; ++r)
        unsafeAtomicAdd(Ob + (g * 16 + fq * 4 + r) * DH + c4 * 16 + fm, o[g][c4][r]);
  }
}

// ---------------- combine: Ctx = bf16(Oacc / Lacc) --------------------------
__global__ __launch_bounds__(256) void combine_kernel(const float* __restrict__ Oacc,
                                                      const float* __restrict__ Lacc,
                                                      u16* __restrict__ Ctx) {
  int idx = blockIdx.x * 256 + threadIdx.x;  // 1,048,576 threads
  int d4 = (idx & 15) * 4;
  int hh = (idx >> 4) & 15;
  int row = idx >> 8;
  float4 a = *(const float4*)(Oacc + ((size_t)hh * S_LEN + row) * DH + d4);
  float il = 1.0f / Lacc[hh * S_LEN + row];
  uint2 o;
  o.x = pk2(a.x * il, a.y * il);
  o.y = pk2(a.z * il, a.w * il);
  *(uint2*)(Ctx + (size_t)row * DM + hh * DH + d4) = o;
}

extern "C" void kernel_launch(void* const* d_in, const int* in_sizes, int n_in,
                              void* d_out, int out_size, void* d_ws, size_t ws_size,
                              hipStream_t stream) {
  const float* x  = (const float*)d_in[0];
  const float* Wq = (const float*)d_in[1];
  const float* Wk = (const float*)d_in[2];
  const float* Wv = (const float*)d_in[3];
  const float* Wo = (const float*)d_in[4];
  float* out = (float*)d_out;

  const size_t MB = 1u << 20;
  char* ws = (char*)d_ws;
  // region [0, 16.25 MB): phase 1 = xb(8) + wqb/wkb/wvb(2+2+2); phase 2 = Oacc(16)+Lacc(0.25)
  u16* xb    = (u16*)(ws + 0 * MB);
  u16* wqb   = (u16*)(ws + 8 * MB);
  u16* wkb   = (u16*)(ws + 10 * MB);
  u16* wvb   = (u16*)(ws + 12 * MB);
  float* Oacc = (float*)(ws + 0 * MB);
  float* Lacc = (float*)(ws + 16 * MB);
  u16* wob   = (u16*)(ws + 17 * MB);  // persists to o_gemm
  u16* Qb    = (u16*)(ws + 19 * MB);
  u16* Kb    = (u16*)(ws + 27 * MB);
  u16* Vtb   = (u16*)(ws + 35 * MB);
  u16* Ctx   = (u16*)(ws + 43 * MB);

  cvt_all<<<8192, 256, 0, stream>>>(x, Wq, Wk, Wv, Wo, xb, wqb, wkb, wvb, wob);
  qkv_gemm<<<dim3(24, 32), 256, 0, stream>>>(xb, wqb, wkb, wvb, Qb, Kb, Vtb);
  zero_kernel<<<4160, 256, 0, stream>>>((float4*)Oacc);  // zeros Oacc+Lacc (16.25 MB)
  attn_kernel<<<dim3(64, NH), 256, 0, stream>>>(Qb, Kb, Vtb, Oacc, Lacc);
  combine_kernel<<<4096, 256, 0, stream>>>(Oacc, Lacc, Ctx);
  o_gemm<<<dim3(DM / 128, S_LEN / 128), 256, 0, stream>>>(Ctx, wob, out, S_LEN, DM, DM);
}

// Round 6
// 229.650 us; speedup vs baseline: 2.3075x; 1.0705x over previous
//
#include <hip/hip_runtime.h>
#include <hip/hip_bf16.h>

typedef __attribute__((ext_vector_type(8))) short bf16x8;
typedef __attribute__((ext_vector_type(4))) float f32x4;
typedef unsigned short u16;

#define S_LEN 4096
#define DM 1024
#define NH 16
#define DH 64
#define PSTR 72

// manual RNE fp32->bf16 (inputs never NaN here): 3 VALU ops
__device__ __forceinline__ u16 f2b_rne(float f) {
  unsigned u = __builtin_bit_cast(unsigned, f);
  return (u16)((u + 0x7fffu + ((u >> 16) & 1u)) >> 16);
}
// pack two fp32 -> bf16x2 in one u32 (RNE)
__device__ __forceinline__ unsigned pk2(float a, float b) {
  unsigned ua = __builtin_bit_cast(unsigned, a);
  unsigned ub = __builtin_bit_cast(unsigned, b);
  ua = (ua + 0x7fffu + ((ua >> 16) & 1u)) >> 16;
  ub = (ub + 0x7fffu + ((ub >> 16) & 1u)) & 0xffff0000u;
  return ua | ub;
}
// pack two fp32 -> bf16x2, TRUNCATED: single v_perm_b32.
// bias cancels in softmax (same P in numerator and denominator).
__device__ __forceinline__ unsigned pk2t(float a, float b) {
  return __builtin_amdgcn_perm(__builtin_bit_cast(unsigned, b),
                               __builtin_bit_cast(unsigned, a), 0x07060302u);
}

// global -> LDS direct (16B per lane; lds base must be wave-uniform)
__device__ __forceinline__ void glds16(const u16* g, u16* l) {
  __builtin_amdgcn_global_load_lds(
      (const __attribute__((address_space(1))) unsigned int*)g,
      (__attribute__((address_space(3))) unsigned int*)l, 16, 0, 0);
}

// ---------------- fp32 -> bf16, all 5 inputs in one launch ----------------
__global__ __launch_bounds__(256) void cvt_all(const float* __restrict__ x,
                                               const float* __restrict__ Wq,
                                               const float* __restrict__ Wk,
                                               const float* __restrict__ Wv,
                                               const float* __restrict__ Wo,
                                               u16* __restrict__ xb, u16* __restrict__ wqb,
                                               u16* __restrict__ wkb, u16* __restrict__ wvb,
                                               u16* __restrict__ wob) {
  int idx = (blockIdx.x * 256 + threadIdx.x) * 4;
  const float* src;
  u16* dst;
  int o;
  if (idx < 4194304) {
    src = x; dst = xb; o = idx;
  } else {
    int t = idx - 4194304;
    int wsel = t >> 20;
    o = t & 1048575;
    src = (wsel == 0) ? Wq : (wsel == 1) ? Wk : (wsel == 2) ? Wv : Wo;
    dst = (wsel == 0) ? wqb : (wsel == 1) ? wkb : (wsel == 2) ? wvb : wob;
  }
  float4 v = *(const float4*)(src + o);
  uint2 ov;
  ov.x = pk2(v.x, v.y);
  ov.y = pk2(v.z, v.w);
  *(uint2*)(dst + o) = ov;
}

// ---------------- zero the O/L accumulators (16 MB + 256 KB) ---------------
__global__ __launch_bounds__(256) void zero_kernel(float4* __restrict__ p) {
  p[blockIdx.x * 256 + threadIdx.x] = float4{0.f, 0.f, 0.f, 0.f};
}

// ---------------- fused QKV NT-GEMM with RoPE epilogue; V written transposed
// grid (24, 32): mat = bx>>3 (0=Q rope+scale, 1=K rope, 2=V -> Vt), nb = (bx&7)*128
__global__ __launch_bounds__(256) void qkv_gemm(const u16* __restrict__ A,
                                                const u16* __restrict__ Wq,
                                                const u16* __restrict__ Wk,
                                                const u16* __restrict__ Wv,
                                                u16* __restrict__ Qo, u16* __restrict__ Ko,
                                                u16* __restrict__ Vt) {
  __shared__ __align__(16) u16 As[2 * 128 * 32];
  __shared__ __align__(16) u16 Bs[2 * 128 * 32];
  const int mat = blockIdx.x >> 3;
  const u16* B = (mat == 0) ? Wq : (mat == 1) ? Wk : Wv;
  const int K = DM, N = DM;
  const int tid = threadIdx.x;
  const int wave = tid >> 6, lane = tid & 63;
  const int fm = lane & 15, fq = lane >> 4;
  const int mb = blockIdx.y * 128, nb = (blockIdx.x & 7) * 128;
  const int wm = (wave & 1) * 64, wn = (wave >> 1) * 64;

  f32x4 acc[4][4];
#pragma unroll
  for (int i = 0; i < 4; ++i)
#pragma unroll
    for (int j = 0; j < 4; ++j)
#pragma unroll
      for (int r = 0; r < 4; ++r) acc[i][j][r] = 0.f;

  const int r_ = tid >> 2;
  const int cg = (tid & 3) ^ ((r_ >> 1) & 3);
  const u16* Ag0 = A + (size_t)(mb + r_) * K + cg * 8;
  const u16* Ag1 = A + (size_t)(mb + r_ + 64) * K + cg * 8;
  const u16* Bg0 = B + (size_t)(nb + r_) * K + cg * 8;
  const u16* Bg1 = B + (size_t)(nb + r_ + 64) * K + cg * 8;
  const int l0 = wave * 512;
  const int l1 = 2048 + wave * 512;
  const int sw = (fm >> 1) & 3;

  int buf = 0;
  glds16(Ag0, As + l0);
  glds16(Ag1, As + l1);
  glds16(Bg0, Bs + l0);
  glds16(Bg1, Bs + l1);

  for (int k0 = 0; k0 < K; k0 += 32) {
    __syncthreads();
    if (k0 + 32 < K) {
      int bo = (buf ^ 1) * 4096;
      glds16(Ag0 + k0 + 32, As + bo + l0);
      glds16(Ag1 + k0 + 32, As + bo + l1);
      glds16(Bg0 + k0 + 32, Bs + bo + l0);
      glds16(Bg1 + k0 + 32, Bs + bo + l1);
    }
    const u16* Ab = As + buf * 4096;
    const u16* Bb = Bs + buf * 4096;
    bf16x8 av[4], bv[4];
#pragma unroll
    for (int t = 0; t < 4; ++t) {
      av[t] = *(const bf16x8*)(Ab + (wm + t * 16 + fm) * 32 + ((fq ^ sw) * 8));
      bv[t] = *(const bf16x8*)(Bb + (wn + t * 16 + fm) * 32 + ((fq ^ sw) * 8));
    }
#pragma unroll
    for (int i = 0; i < 4; ++i)
#pragma unroll
      for (int j = 0; j < 4; ++j)
        acc[i][j] = __builtin_amdgcn_mfma_f32_16x16x32_bf16(av[i], bv[j], acc[i][j], 0, 0, 0);
    buf ^= 1;
  }

  if (mat < 2) {
    // RoPE epilogue (in-register): pairs (d, d+32) = regs (j, j+2), d = j*16+fm, j in {0,1}
    u16* Out = (mat == 0) ? Qo : Ko;
    const float qs = (mat == 0) ? 0.1803368801111204f : 1.0f;  // 0.125*log2(e) for Q
    const float c1 = -9.2103403719761836f / 32.f;              // -ln(10000)/32
    const float if0 = __expf((float)fm * c1);
    const float if1 = __expf((float)(16 + fm) * c1);
#pragma unroll
    for (int ii = 0; ii < 4; ++ii) {
#pragma unroll
      for (int r = 0; r < 4; ++r) {
        float s = (float)(mb + wm + ii * 16 + fq * 4 + r);
#pragma unroll
        for (int jp = 0; jp < 2; ++jp) {
          float ang = s * (jp ? if1 : if0);
          float sn, cs;
          __sincosf(ang, &sn, &cs);
          float a = acc[ii][jp][r], b = acc[ii][jp + 2][r];
          acc[ii][jp][r] = (a * cs - b * sn) * qs;
          acc[ii][jp + 2][r] = (b * cs + a * sn) * qs;
        }
      }
    }
#pragma unroll
    for (int i = 0; i < 4; ++i)
#pragma unroll
      for (int j = 0; j < 4; ++j)
#pragma unroll
        for (int r = 0; r < 4; ++r) {
          int row = mb + wm + i * 16 + fq * 4 + r;
          int col = nb + wn + j * 16 + fm;
          Out[(size_t)row * N + col] = f2b_rne(acc[i][j][r]);
        }
  } else {
    // V: write transposed Vt[col][row]; 4 r-values are contiguous rows -> 8B store
#pragma unroll
    for (int i = 0; i < 4; ++i)
#pragma unroll
      for (int j = 0; j < 4; ++j) {
        int col = nb + wn + j * 16 + fm;
        int row0 = mb + wm + i * 16 + fq * 4;
        uint2 pv;
        pv.x = pk2(acc[i][j][0], acc[i][j][1]);
        pv.y = pk2(acc[i][j][2], acc[i][j][3]);
        *(uint2*)(Vt + (size_t)col * S_LEN + row0) = pv;
      }
  }
}

// ---------------- O-projection NT GEMM, 64x128 tiles (fp32 out) -------------
// grid (8, 64): nb = bx*128, mb = by*64. 512 blocks -> real occupancy (vs 256).
__global__ __launch_bounds__(256) void o_gemm(const u16* __restrict__ A,
                                              const u16* __restrict__ B,
                                              float* __restrict__ C, int M, int N, int K) {
  __shared__ __align__(16) u16 As[2 * 64 * 32];
  __shared__ __align__(16) u16 Bs[2 * 128 * 32];
  const int tid = threadIdx.x;
  const int wave = tid >> 6, lane = tid & 63;
  const int fm = lane & 15, fq = lane >> 4;
  const int mb = blockIdx.y * 64, nb = blockIdx.x * 128;
  const int wm = (wave & 1) * 32, wn = (wave >> 1) * 64;

  f32x4 acc[2][4];
#pragma unroll
  for (int i = 0; i < 2; ++i)
#pragma unroll
    for (int j = 0; j < 4; ++j)
#pragma unroll
      for (int r = 0; r < 4; ++r) acc[i][j][r] = 0.f;

  const int r_ = tid >> 2;
  const int cg = (tid & 3) ^ ((r_ >> 1) & 3);
  const u16* Ag0 = A + (size_t)(mb + r_) * K + cg * 8;
  const u16* Bg0 = B + (size_t)(nb + r_) * K + cg * 8;
  const u16* Bg1 = B + (size_t)(nb + r_ + 64) * K + cg * 8;
  const int l0 = wave * 512;
  const int l1 = 2048 + wave * 512;
  const int sw = (fm >> 1) & 3;

  int buf = 0;
  glds16(Ag0, As + l0);
  glds16(Bg0, Bs + l0);
  glds16(Bg1, Bs + l1);

  for (int k0 = 0; k0 < K; k0 += 32) {
    __syncthreads();
    if (k0 + 32 < K) {
      int aoff = (buf ^ 1) * 2048, boff = (buf ^ 1) * 4096;
      glds16(Ag0 + k0 + 32, As + aoff + l0);
      glds16(Bg0 + k0 + 32, Bs + boff + l0);
      glds16(Bg1 + k0 + 32, Bs + boff + l1);
    }
    const u16* Ab = As + buf * 2048;
    const u16* Bb = Bs + buf * 4096;
    bf16x8 av[2], bv[4];
#pragma unroll
    for (int t = 0; t < 2; ++t)
      av[t] = *(const bf16x8*)(Ab + (wm + t * 16 + fm) * 32 + ((fq ^ sw) * 8));
#pragma unroll
    for (int t = 0; t < 4; ++t)
      bv[t] = *(const bf16x8*)(Bb + (wn + t * 16 + fm) * 32 + ((fq ^ sw) * 8));
#pragma unroll
    for (int i = 0; i < 2; ++i)
#pragma unroll
      for (int j = 0; j < 4; ++j)
        acc[i][j] = __builtin_amdgcn_mfma_f32_16x16x32_bf16(av[i], bv[j], acc[i][j], 0, 0, 0);
    buf ^= 1;
  }
#pragma unroll
  for (int i = 0; i < 2; ++i)
#pragma unroll
    for (int j = 0; j < 4; ++j)
#pragma unroll
      for (int r = 0; r < 4; ++r) {
        int row = mb + wm + i * 16 + fq * 4 + r;
        int col = nb + wn + j * 16 + fm;
        C[(size_t)row * N + col] = acc[i][j][r];
      }
}

// ---------------- causal flash attention v6: 8-wave blocks ------------------
// 512 threads, 256 q-rows/block; 8 waves share each staged 64x64 K/V tile
// (one glds16 per tile per array). Split-K (half), fixed-m exp2 softmax,
// ones-MFMA lsum, v_perm P-pack, g-sequential per-wave Ps (per-wave DS FIFO
// makes write(g1)-after-read(g0) safe). Grid 512 1D, complement-paired so
// blocks i and i+256 have qt and 15-qt (constant per-CU work).
__global__ __launch_bounds__(512, 4) void attn_kernel(const u16* __restrict__ Q,
                                                      const u16* __restrict__ K,
                                                      const u16* __restrict__ Vt,
                                                      float* __restrict__ Oacc,
                                                      float* __restrict__ Lacc) {
  __shared__ __align__(16) u16 Ks[2 * 4096];   // 2 x (64 key x 64 d), swizzled
  __shared__ __align__(16) u16 Vs[2 * 4096];   // 2 x (64 d x 64 key), swizzled
  __shared__ __align__(16) u16 Ps[8][16 * PSTR];  // per-wave, g-sequential
  const int tid = threadIdx.x;
  const int w = tid >> 6, lane = tid & 63;
  const int fm = lane & 15, fq = lane >> 4;
  const int bid = blockIdx.x;       // [0,512)
  const int u = bid & 255, hi = bid >> 8;
  const int h = u & 15;
  const int qt0 = u >> 4;           // [0,16)
  const int qt = hi ? qt0 : 15 - qt0;
  const int half = hi;
  const int qb = qt * 256 + w * 32;
  const int nlocal = 2 * qt + 2;    // tiles per half (total 4qt+4)
  const int kbase = half * nlocal;
  const int dtile = qb >> 6;        // == dtile: partial mask; > dtile: skip

  bf16x8 q0[2], q1[2];
#pragma unroll
  for (int g = 0; g < 2; ++g) {
    const u16* qp = Q + (size_t)(qb + g * 16 + fm) * DM + h * DH + fq * 8;
    q0[g] = *(const bf16x8*)(qp);
    q1[g] = *(const bf16x8*)(qp + 32);
  }
  f32x4 o[2][4];
  f32x4 ls[2];
#pragma unroll
  for (int g = 0; g < 2; ++g) {
#pragma unroll
    for (int r = 0; r < 4; ++r) ls[g][r] = 0.f;
#pragma unroll
    for (int c4 = 0; c4 < 4; ++c4)
#pragma unroll
      for (int r = 0; r < 4; ++r) o[g][c4][r] = 0.f;
  }
  const short ONEB = (short)0x3F80;  // 1.0 bf16
  const bf16x8 vone = {ONEB, ONEB, ONEB, ONEB, ONEB, ONEB, ONEB, ONEB};

  // staging: 512 slots x 16B = one full 64x64 tile; slot = tid.
  // row = tid>>3, stored chunk = tid&7, global chunk = (tid&7) ^ (row&7).
  const int rr = tid >> 3;                 // [0,64)
  const int cc8 = (tid & 7) ^ (rr & 7);
  const u16* Kg = K + (size_t)rr * DM + h * DH + cc8 * 8;
  const u16* Vg = Vt + (size_t)(h * DH + rr) * S_LEN + cc8 * 8;
  const int l0 = w * 512;                  // wave-uniform LDS base (u16)
  const int sw7 = fm & 7;
  const f32x4 zf = {0.f, 0.f, 0.f, 0.f};

  glds16(Kg + (size_t)kbase * 64 * DM, Ks + l0);
  glds16(Vg + kbase * 64, Vs + l0);

  int buf = 0;
  for (int kl = 0; kl < nlocal; ++kl) {
    const int ktg = kbase + kl;
    __syncthreads();
    if (kl + 1 < nlocal) {
      int bo = (buf ^ 1) * 4096;
      glds16(Kg + (size_t)(ktg + 1) * 64 * DM, Ks + bo + l0);
      glds16(Vg + (ktg + 1) * 64, Vs + bo + l0);
    }
    if (ktg <= dtile) {
      const u16* Kb = Ks + buf * 4096;
      const u16* Vb = Vs + buf * 4096;

      // S^T = K * Q^T : D[key][q]
      f32x4 st[2][4];
#pragma unroll
      for (int t = 0; t < 4; ++t) {
        const u16* kr = Kb + (t * 16 + fm) * 64;
        bf16x8 ka = *(const bf16x8*)(kr + ((fq ^ sw7) * 8));
        bf16x8 kb2 = *(const bf16x8*)(kr + (((fq + 4) ^ sw7) * 8));
#pragma unroll
        for (int g = 0; g < 2; ++g) {
          f32x4 s = __builtin_amdgcn_mfma_f32_16x16x32_bf16(ka, q0[g], zf, 0, 0, 0);
          st[g][t] = __builtin_amdgcn_mfma_f32_16x16x32_bf16(kb2, q1[g], s, 0, 0, 0);
        }
      }
      if (ktg == dtile) {  // diagonal tile: partial causal mask
#pragma unroll
        for (int g = 0; g < 2; ++g) {
          int qg = qb + g * 16 + fm;
#pragma unroll
          for (int t = 0; t < 4; ++t) {
            int key = ktg * 64 + t * 16 + fq * 4;
#pragma unroll
            for (int r = 0; r < 4; ++r)
              st[g][t][r] = (key + r > qg) ? -1e30f : st[g][t][r];
          }
        }
      }
      // V B-operand fragments (shared across g)
      bf16x8 pvb[4][2];
#pragma unroll
      for (int c4 = 0; c4 < 4; ++c4) {
        const u16* vr = Vb + (c4 * 16 + fm) * 64;
        pvb[c4][0] = *(const bf16x8*)(vr + ((fq ^ sw7) * 8));
        pvb[c4][1] = *(const bf16x8*)(vr + (((fq + 4) ^ sw7) * 8));
      }
      // g-sequential: exp2 -> pack -> LDS -> A-frag -> MFMAs, one g at a time
#pragma unroll
      for (int g = 0; g < 2; ++g) {
#pragma unroll
        for (int t = 0; t < 4; ++t) {
          float p0 = __builtin_amdgcn_exp2f(st[g][t][0]);
          float p1 = __builtin_amdgcn_exp2f(st[g][t][1]);
          float p2 = __builtin_amdgcn_exp2f(st[g][t][2]);
          float p3 = __builtin_amdgcn_exp2f(st[g][t][3]);
          uint2 pk;
          pk.x = pk2t(p0, p1);
          pk.y = pk2t(p2, p3);
          *(uint2*)(&Ps[w][fm * PSTR + t * 16 + fq * 4]) = pk;
        }
        asm volatile("s_waitcnt lgkmcnt(0)" ::: "memory");
        bf16x8 ap0 = *(const bf16x8*)(&Ps[w][fm * PSTR + fq * 8]);
        bf16x8 ap1 = *(const bf16x8*)(&Ps[w][fm * PSTR + 32 + fq * 8]);
        ls[g] = __builtin_amdgcn_mfma_f32_16x16x32_bf16(ap0, vone, ls[g], 0, 0, 0);
        ls[g] = __builtin_amdgcn_mfma_f32_16x16x32_bf16(ap1, vone, ls[g], 0, 0, 0);
#pragma unroll
        for (int c4 = 0; c4 < 4; ++c4) {
          o[g][c4] = __builtin_amdgcn_mfma_f32_16x16x32_bf16(ap0, pvb[c4][0], o[g][c4], 0, 0, 0);
          o[g][c4] = __builtin_amdgcn_mfma_f32_16x16x32_bf16(ap1, pvb[c4][1], o[g][c4], 0, 0, 0);
        }
      }
    }
    buf ^= 1;
  }
  // accumulate partials: Oacc[h][row][d], Lacc[h][row]; ls rows = o rows = fq*4+r
  float* Ob = Oacc + ((size_t)h * S_LEN + qt * 256 + w * 32) * DH;
  float* Lb = Lacc + h * S_LEN + qt * 256 + w * 32;
#pragma unroll
  for (int g = 0; g < 2; ++g) {
    if (fm == 0) {
#pragma unroll
      for (int r = 0; r < 4; ++r)
        unsafeAtomicAdd(Lb + g * 16 + fq * 4 + r, ls[g][r]);
    }
#pragma unroll
    for (int c4 = 0; c4 < 4; ++c4)
#pragma unroll
      for (int r = 0; r < 4; ++r)
        unsafeAtomicAdd(Ob + (g * 16 + fq * 4 + r) * DH + c4 * 16 + fm, o[g][c4][r]);
  }
}

// ---------------- combine: Ctx = bf16(Oacc / Lacc) --------------------------
__global__ __launch_bounds__(256) void combine_kernel(const float* __restrict__ Oacc,
                                                      const float* __restrict__ Lacc,
                                                      u16* __restrict__ Ctx) {
  int idx = blockIdx.x * 256 + threadIdx.x;  // 1,048,576 threads
  int d4 = (idx & 15) * 4;
  int hh = (idx >> 4) & 15;
  int row = idx >> 8;
  float4 a = *(const float4*)(Oacc + ((size_t)hh * S_LEN + row) * DH + d4);
  float il = 1.0f / Lacc[hh * S_LEN + row];
  uint2 o;
  o.x = pk2(a.x * il, a.y * il);
  o.y = pk2(a.z * il, a.w * il);
  *(uint2*)(Ctx + (size_t)row * DM + hh * DH + d4) = o;
}

extern "C" void kernel_launch(void* const* d_in, const int* in_sizes, int n_in,
                              void* d_out, int out_size, void* d_ws, size_t ws_size,
                              hipStream_t stream) {
  const float* x  = (const float*)d_in[0];
  const float* Wq = (const float*)d_in[1];
  const float* Wk = (const float*)d_in[2];
  const float* Wv = (const float*)d_in[3];
  const float* Wo = (const float*)d_in[4];
  float* out = (float*)d_out;

  const size_t MB = 1u << 20;
  char* ws = (char*)d_ws;
  // region [0, 16.25 MB): phase 1 = xb(8) + wqb/wkb/wvb(2+2+2); phase 2 = Oacc(16)+Lacc(0.25)
  u16* xb    = (u16*)(ws + 0 * MB);
  u16* wqb   = (u16*)(ws + 8 * MB);
  u16* wkb   = (u16*)(ws + 10 * MB);
  u16* wvb   = (u16*)(ws + 12 * MB);
  float* Oacc = (float*)(ws + 0 * MB);
  float* Lacc = (float*)(ws + 16 * MB);
  u16* wob   = (u16*)(ws + 17 * MB);  // persists to o_gemm
  u16* Qb    = (u16*)(ws + 19 * MB);
  u16* Kb    = (u16*)(ws + 27 * MB);
  u16* Vtb   = (u16*)(ws + 35 * MB);
  u16* Ctx   = (u16*)(ws + 43 * MB);

  cvt_all<<<8192, 256, 0, stream>>>(x, Wq, Wk, Wv, Wo, xb, wqb, wkb, wvb, wob);
  qkv_gemm<<<dim3(24, 32), 256, 0, stream>>>(xb, wqb, wkb, wvb, Qb, Kb, Vtb);
  zero_kernel<<<4160, 256, 0, stream>>>((float4*)Oacc);  // zeros Oacc+Lacc (16.25 MB)
  attn_kernel<<<512, 512, 0, stream>>>(Qb, Kb, Vtb, Oacc, Lacc);
  combine_kernel<<<4096, 256, 0, stream>>>(Oacc, Lacc, Ctx);
  o_gemm<<<dim3(8, 64), 256, 0, stream>>>(Ctx, wob, out, S_LEN, DM, DM);
}